// Round 2
// baseline (4620.872 us; speedup 1.0000x reference)
//
#include <hip/hip_runtime.h>
#include <cmath>

// ---------------------------------------------------------------------------
// SutraV04: patch-GRU + message passing + sparse retrieval LM block.
// B=32, T=2048, PS=4, D=256, N=512 patches/batch, BN=16384, V=256.
// fp32 baseline, lean workspace (~112 MB): local/final lives in d_out.
// ---------------------------------------------------------------------------

constexpr int D_   = 256;
constexpr int N_   = 512;       // patches per batch
constexpr int B_   = 32;
constexpr int BN_  = B_ * N_;   // 16384
constexpr int M1_  = BN_ * 4;   // 65536 (B*N*PS rows)

__device__ __forceinline__ float gelu_f(float x) {
  return 0.5f * x * (1.0f + erff(x * 0.70710678118654752440f));
}
__device__ __forceinline__ float sigm_f(float x) {
  return 1.0f / (1.0f + expf(-x));
}

// ---- A-operand gather modes -----------------------------------------------
// 0: plain row-major A (lda = K)
// 1: GRU input:  emb[xi[m*4+t]][k] + pos[t][k]   (xi pre-offset per chunk)
// 2: msg concat for neighbor slot t=kk: k<256 -> h[m][k], else h[nbr][k-256]
// 3: upd concat: k<256 -> h[m][k], else msgs[m][k-256] / counts(m)
// 4: summaries:  mean over PS of local[(m*4+t)][k]
// 5: add two:    A[m][k] + P2[m][k]
template<int MODE>
__device__ __forceinline__ float loadA(const float* __restrict__ A,
                                       const float* __restrict__ P2,
                                       const int*   __restrict__ xi,
                                       const float* __restrict__ emb,
                                       const float* __restrict__ pos,
                                       int t, int m, int k, int K)
{
  if constexpr (MODE == 0) {
    return A[(size_t)m * K + k];
  } else if constexpr (MODE == 1) {
    int tok = xi[m * 4 + t];
    return emb[tok * 256 + k] + pos[t * 256 + k];
  } else if constexpr (MODE == 2) {
    if (k < 256) return A[(size_t)m * 256 + k];
    int n   = m & (N_ - 1);
    int idx = n + t - 4;          // t = kk in 0..4
    if (idx < 0) idx = 0;
    return A[(size_t)(m - n + idx) * 256 + (k - 256)];
  } else if constexpr (MODE == 3) {
    if (k < 256) return A[(size_t)m * 256 + k];
    int n = m & (N_ - 1);
    int cnt = (n < 4 ? n : 4) + 1;
    return P2[(size_t)m * 256 + (k - 256)] * (1.0f / (float)cnt);
  } else if constexpr (MODE == 4) {
    const float* p = A + (size_t)m * 1024 + k;
    return 0.25f * (p[0] + p[256] + p[512] + p[768]);
  } else {
    return A[(size_t)m * 256 + k] + P2[(size_t)m * 256 + k];
  }
}

// ---- generic tiled GEMM: C[M,N] = epi(act(gatherA @ B (+bias))) -----------
// BT=false: B row-major (K,N).  BT=true: B = W^T with W row-major (N,K).
// ACT: 0 none, 1 exact gelu.
// EPI: 0 store; 1 accumulate C += v masked by neighbor-validity (t = kk).
template<int MODE, bool BT, int ACT, int EPI>
__global__ __launch_bounds__(256)
void gemm_k(const float* __restrict__ A, const float* __restrict__ Bm,
            const float* __restrict__ bias, float* __restrict__ C,
            int M, int Nn, int K,
            const float* __restrict__ P2,
            const int*   __restrict__ xi,
            const float* __restrict__ emb,
            const float* __restrict__ pos,
            int t)
{
  __shared__ float As[16][64];
  __shared__ float Bs[16][64];
  const int tid = threadIdx.x;
  const int tx = tid & 15, ty = tid >> 4;
  const int m0 = blockIdx.y * 64, n0 = blockIdx.x * 64;

  float acc[4][4] = {};

  for (int k0 = 0; k0 < K; k0 += 16) {
    // A tile (stored transposed: As[k][m])
    {
      int l  = tid * 4;
      int ml = l >> 4, kl = l & 15;
      #pragma unroll
      for (int j = 0; j < 4; ++j)
        As[kl + j][ml] = loadA<MODE>(A, P2, xi, emb, pos, t, m0 + ml, k0 + kl + j, K);
    }
    // B tile (Bs[k][n])
    if (!BT) {
      int l  = tid * 4;
      int kl = l >> 6, nl = l & 63;
      #pragma unroll
      for (int j = 0; j < 4; ++j)
        Bs[kl][nl + j] = Bm[(size_t)(k0 + kl) * Nn + (n0 + nl + j)];
    } else {
      int l  = tid * 4;
      int nl = l >> 4, kl = l & 15;
      #pragma unroll
      for (int j = 0; j < 4; ++j)
        Bs[kl + j][nl] = Bm[(size_t)(n0 + nl) * K + (k0 + kl + j)];
    }
    __syncthreads();

    #pragma unroll
    for (int kk = 0; kk < 16; ++kk) {
      float a[4], b[4];
      #pragma unroll
      for (int r = 0; r < 4; ++r) a[r] = As[kk][ty * 4 + r];
      #pragma unroll
      for (int c = 0; c < 4; ++c) b[c] = Bs[kk][tx * 4 + c];
      #pragma unroll
      for (int r = 0; r < 4; ++r)
        #pragma unroll
        for (int c = 0; c < 4; ++c)
          acc[r][c] += a[r] * b[c];
    }
    __syncthreads();
  }

  #pragma unroll
  for (int r = 0; r < 4; ++r) {
    int row = m0 + ty * 4 + r;
    #pragma unroll
    for (int c = 0; c < 4; ++c) {
      int col = n0 + tx * 4 + c;
      float v = acc[r][c];
      if (bias) v += bias[col];
      if constexpr (ACT == 1) v = gelu_f(v);
      if constexpr (EPI == 0) {
        C[(size_t)row * Nn + col] = v;
      } else {
        int n = row & (N_ - 1);
        if (n + t - 4 >= 0) C[(size_t)row * Nn + col] += v;
      }
    }
  }
}

// ---- GRU pointwise step (chunk-local) -------------------------------------
__global__ __launch_bounds__(256)
void gru_pw_k(const float* __restrict__ xg, const float* __restrict__ gh,
              float* __restrict__ h, float* __restrict__ local, int t)
{
  int i   = blockIdx.x * 256 + threadIdx.x;
  int row = i >> 8, d = i & 255;
  const float* xr = xg + (size_t)row * 768;
  const float* gr = gh + (size_t)row * 768;
  float ir = xr[d],      iz = xr[256 + d], inn = xr[512 + d];
  float hr = gr[d],      hz = gr[256 + d], hn  = gr[512 + d];
  float hprev = h[i];
  float r  = sigm_f(ir + hr);
  float z  = sigm_f(iz + hz);
  float nn = tanhf(inn + r * hn);
  float hnew = (1.0f - z) * nn + z * hprev;
  h[i] = hnew;
  local[((size_t)row * 4 + t) * 256 + d] = hnew;
}

// ---- LayerNorm (optionally Y = LN(X + Add[row>>shift])) in place ----------
__global__ __launch_bounds__(256)
void ln_k(float* __restrict__ X, const float* __restrict__ Add, int addShift,
          const float* __restrict__ g, const float* __restrict__ bb, int rows)
{
  int wave = threadIdx.x >> 6, lane = threadIdx.x & 63;
  int row  = blockIdx.x * 4 + wave;
  if (row >= rows) return;
  float* xr = X + (size_t)row * 256;
  float x[4];
  #pragma unroll
  for (int j = 0; j < 4; ++j) x[j] = xr[lane * 4 + j];
  if (Add) {
    const float* ar = Add + (size_t)(row >> addShift) * 256;
    #pragma unroll
    for (int j = 0; j < 4; ++j) x[j] += ar[lane * 4 + j];
  }
  float s = x[0] + x[1] + x[2] + x[3];
  #pragma unroll
  for (int off = 1; off < 64; off <<= 1) s += __shfl_xor(s, off, 64);
  float mean = s * (1.0f / 256.0f);
  float ss = 0.f;
  #pragma unroll
  for (int j = 0; j < 4; ++j) { float d = x[j] - mean; ss += d * d; }
  #pragma unroll
  for (int off = 1; off < 64; off <<= 1) ss += __shfl_xor(ss, off, 64);
  float inv = rsqrtf(ss * (1.0f / 256.0f) + 1e-5f);
  #pragma unroll
  for (int j = 0; j < 4; ++j)
    xr[lane * 4 + j] = (x[j] - mean) * inv * g[lane * 4 + j] + bb[lane * 4 + j];
}

// ---- halting probability per batch ----------------------------------------
__global__ __launch_bounds__(256)
void halt_k(const float* __restrict__ h, const float* __restrict__ hw,
            const float* __restrict__ hb, float* __restrict__ hp)
{
  int b = blockIdx.x, tid = threadIdx.x;
  const float* hbp = h + (size_t)b * N_ * 256;
  float acc = 0.f;
  for (int i = tid; i < N_ * 256; i += 256) acc += hbp[i] * hw[i & 255];
  __shared__ float red[256];
  red[tid] = acc; __syncthreads();
  for (int off = 128; off > 0; off >>= 1) {
    if (tid < off) red[tid] += red[tid + off];
    __syncthreads();
  }
  if (tid == 0) hp[b] = sigm_f(red[0] * (1.0f / (float)N_) + hb[0]);
}

__global__ __launch_bounds__(256)
void out2_k(const float* __restrict__ h, const float* __restrict__ hp,
            float* __restrict__ outp)
{
  int i = blockIdx.x * 256 + threadIdx.x;
  outp[i] = hp[i >> 17] * h[i];
}
__global__ __launch_bounds__(256)
void out3_k(const float* __restrict__ h, const float* __restrict__ hp,
            float* __restrict__ outp)
{
  int i = blockIdx.x * 256 + threadIdx.x;
  outp[i] += (1.0f - hp[i >> 17]) * h[i];
}

// ---- batched causal scores for 16 batches starting at b0 ------------------
__global__ __launch_bounds__(256)
void scores_k(const float* __restrict__ q, const float* __restrict__ kmat,
              float* __restrict__ s, int b0)
{
  int bl = blockIdx.z;           // local batch 0..15
  int b  = b0 + bl;
  const float* qb = q    + (size_t)b * N_ * 256;
  const float* kb = kmat + (size_t)b * N_ * 256;
  __shared__ float As[16][64];
  __shared__ float Bs[16][64];
  const int tid = threadIdx.x;
  const int tx = tid & 15, ty = tid >> 4;
  const int m0 = blockIdx.y * 64, n0 = blockIdx.x * 64;
  float acc[4][4] = {};
  for (int k0 = 0; k0 < 256; k0 += 16) {
    int l = tid * 4;
    int ml = l >> 4, kl = l & 15;
    #pragma unroll
    for (int j = 0; j < 4; ++j) {
      As[kl + j][ml] = qb[(size_t)(m0 + ml) * 256 + k0 + kl + j];
      Bs[kl + j][ml] = kb[(size_t)(n0 + ml) * 256 + k0 + kl + j];
    }
    __syncthreads();
    #pragma unroll
    for (int kk = 0; kk < 16; ++kk) {
      float a[4], bb2[4];
      #pragma unroll
      for (int r = 0; r < 4; ++r) a[r] = As[kk][ty * 4 + r];
      #pragma unroll
      for (int c = 0; c < 4; ++c) bb2[c] = Bs[kk][tx * 4 + c];
      #pragma unroll
      for (int r = 0; r < 4; ++r)
        #pragma unroll
        for (int c = 0; c < 4; ++c)
          acc[r][c] += a[r] * bb2[c];
    }
    __syncthreads();
  }
  #pragma unroll
  for (int r = 0; r < 4; ++r) {
    int row = m0 + ty * 4 + r;
    #pragma unroll
    for (int c = 0; c < 4; ++c) {
      int col = n0 + tx * 4 + c;
      float v = acc[r][c] * (1.0f / 16.0f);
      if (col > row) v = -__builtin_inff();
      s[((size_t)bl * N_ + row) * N_ + col] = v;
    }
  }
}

// ---- per-row top-8 + softmax + weighted V gather (rows r0..r0+8191) -------
__global__ __launch_bounds__(256)
void topk_k(const float* __restrict__ s, const float* __restrict__ v,
            float* __restrict__ rpre, int r0)
{
  int rowg = r0 + blockIdx.x;
  int b = rowg >> 9;
  const float* srow = s + (size_t)blockIdx.x * N_;
  __shared__ float sv[512];
  __shared__ float redV[256];
  __shared__ int   redI[256];
  __shared__ float topv[8];
  __shared__ int   topi[8];
  __shared__ float wsh[8];
  int tid = threadIdx.x;
  sv[tid] = srow[tid];
  sv[tid + 256] = srow[tid + 256];
  __syncthreads();
  for (int it = 0; it < 8; ++it) {
    float v0 = sv[tid], v1 = sv[tid + 256];
    float bv; int bi;
    if (v1 > v0) { bv = v1; bi = tid + 256; } else { bv = v0; bi = tid; }
    redV[tid] = bv; redI[tid] = bi;
    __syncthreads();
    for (int off = 128; off > 0; off >>= 1) {
      if (tid < off) {
        float ov = redV[tid + off]; int oi = redI[tid + off];
        if (ov > redV[tid] || (ov == redV[tid] && oi < redI[tid])) {
          redV[tid] = ov; redI[tid] = oi;
        }
      }
      __syncthreads();
    }
    if (tid == 0) {
      topv[it] = redV[0]; topi[it] = redI[0];
      sv[redI[0]] = -__builtin_inff();
    }
    __syncthreads();
  }
  if (tid == 0) {
    float mx = topv[0];
    float ssum = 0.f;
    for (int j = 0; j < 8; ++j) { float e = expf(topv[j] - mx); wsh[j] = e; ssum += e; }
    float inv = 1.0f / ssum;
    for (int j = 0; j < 8; ++j) wsh[j] *= inv;
  }
  __syncthreads();
  float acc = 0.f;
  #pragma unroll
  for (int j = 0; j < 8; ++j)
    acc += wsh[j] * v[((size_t)(b * N_ + topi[j])) * 256 + tid];
  rpre[(size_t)rowg * 256 + tid] = acc;
}

// ---- KL scalar -------------------------------------------------------------
__global__ void kl_k(const float* __restrict__ hp, float* __restrict__ out)
{
  if (threadIdx.x == 0 && blockIdx.x == 0) {
    float hm = 0.f;
    for (int b = 0; b < 32; ++b) hm += hp[b];
    hm *= (1.0f / 32.0f);
    const float l1e8 = logf(1e-8f);
    float kl = 0.f;
    kl += 0.2f    * (logf(0.2f)    - l1e8);
    kl += 0.16f   * (logf(0.16f)   - l1e8);
    kl += 0.128f  * (logf(0.128f)  - logf(hm + 1e-8f));
    kl += 0.1024f * (logf(0.1024f) - logf(1.0f + 1e-8f));
    out[0] = kl * 0.25f;
  }
}

// ---------------------------------------------------------------------------
extern "C" void kernel_launch(void* const* d_in, const int* in_sizes, int n_in,
                              void* d_out, int out_size, void* d_ws, size_t ws_size,
                              hipStream_t stream)
{
  const int*   x       = (const int*)  d_in[0];
  const float* emb     = (const float*)d_in[1];
  const float* pos     = (const float*)d_in[2];
  const float* gru_wih = (const float*)d_in[3];
  const float* gru_whh = (const float*)d_in[4];
  const float* gru_bih = (const float*)d_in[5];
  const float* gru_bhh = (const float*)d_in[6];
  const float* pp_ln_g = (const float*)d_in[7];
  const float* pp_ln_b = (const float*)d_in[8];
  const float* sum_w   = (const float*)d_in[9];
  const float* sum_b   = (const float*)d_in[10];
  const float* msg_w1  = (const float*)d_in[11];
  const float* msg_b1  = (const float*)d_in[12];
  const float* msg_w2  = (const float*)d_in[13];
  const float* msg_b2  = (const float*)d_in[14];
  const float* upd_w1  = (const float*)d_in[15];
  const float* upd_b1  = (const float*)d_in[16];
  const float* upd_w2  = (const float*)d_in[17];
  const float* upd_b2  = (const float*)d_in[18];
  const float* halt_w  = (const float*)d_in[19];
  const float* halt_b  = (const float*)d_in[20];
  const float* mp_ln_g = (const float*)d_in[21];
  const float* mp_ln_b = (const float*)d_in[22];
  const float* q_w     = (const float*)d_in[23];
  const float* q_b     = (const float*)d_in[24];
  const float* k_w     = (const float*)d_in[25];
  const float* k_b     = (const float*)d_in[26];
  const float* v_w     = (const float*)d_in[27];
  const float* v_b     = (const float*)d_in[28];
  const float* o_w     = (const float*)d_in[29];
  const float* o_b     = (const float*)d_in[30];
  const float* br_w    = (const float*)d_in[31];
  const float* br_b    = (const float*)d_in[32];
  const float* f_ln_g  = (const float*)d_in[33];
  const float* f_ln_b  = (const float*)d_in[34];
  const float* head_w  = (const float*)d_in[35];

  // ---- workspace layout (floats), ~112 MB total ----
  constexpr size_t SZ_Q   = (size_t)BN_ * 256;        // 4,194,304 (16 MB)
  constexpr size_t SZ_BIG = 3 * SZ_Q;                 // 12,582,912 (48 MB)
  float* ws     = (float*)d_ws;
  float* R_h    = ws;
  float* R_outp = R_h    + SZ_Q;
  float* R_msgs = R_outp + SZ_Q;
  float* R_big  = R_msgs + SZ_Q;
  float* R_sc   = R_big  + SZ_BIG;
  float* R_hp   = R_sc   + SZ_Q;

  float* local  = (float*)d_out;      // 16,777,216 floats; logits overwrite it
  float* logits = (float*)d_out;

  dim3 blk(256);
  constexpr int CH = 4096;            // GRU row chunk

  // ---- patch GRU (4 steps, 4 row-chunks) ----
  hipMemsetAsync(R_h, 0, SZ_Q * sizeof(float), stream);
  float* xgc = R_big;
  float* ghc = R_big + (size_t)CH * 768;
  for (int t = 0; t < 4; ++t) {
    for (int c = 0; c < BN_ / CH; ++c) {
      size_t ro = (size_t)c * CH;
      gemm_k<1, true, 0, 0><<<dim3(12, CH / 64), blk, 0, stream>>>(
          nullptr, gru_wih, gru_bih, xgc, CH, 768, 256,
          nullptr, x + ro * 4, emb, pos, t);
      gemm_k<0, true, 0, 0><<<dim3(12, CH / 64), blk, 0, stream>>>(
          R_h + ro * 256, gru_whh, gru_bhh, ghc, CH, 768, 256,
          nullptr, nullptr, nullptr, nullptr, 0);
      gru_pw_k<<<dim3(CH), blk, 0, stream>>>(
          xgc, ghc, R_h + ro * 256, local + ro * 1024, t);
    }
  }
  ln_k<<<dim3(M1_ / 4), blk, 0, stream>>>(local, nullptr, 0, pp_ln_g, pp_ln_b, M1_);

  // summaries -> h
  gemm_k<4, false, 0, 0><<<dim3(4, 256), blk, 0, stream>>>(
      local, sum_w, sum_b, R_h, BN_, 256, 256, nullptr, nullptr, nullptr, nullptr, 0);

  // ---- message-passing rounds ----
  float* hid    = R_big;
  float* updout = R_big + SZ_Q;
  for (int step = 0; step < 4; ++step) {
    hipMemsetAsync(R_msgs, 0, SZ_Q * sizeof(float), stream);
    for (int kk = 0; kk < 5; ++kk) {
      gemm_k<2, false, 1, 0><<<dim3(4, 256), blk, 0, stream>>>(
          R_h, msg_w1, msg_b1, hid, BN_, 256, 512, nullptr, nullptr, nullptr, nullptr, kk);
      gemm_k<0, false, 0, 1><<<dim3(4, 256), blk, 0, stream>>>(
          hid, msg_w2, msg_b2, R_msgs, BN_, 256, 256, nullptr, nullptr, nullptr, nullptr, kk);
    }
    gemm_k<3, false, 1, 0><<<dim3(4, 256), blk, 0, stream>>>(
        R_h, upd_w1, upd_b1, hid, BN_, 256, 512, R_msgs, nullptr, nullptr, nullptr, 0);
    gemm_k<0, false, 0, 0><<<dim3(4, 256), blk, 0, stream>>>(
        hid, upd_w2, upd_b2, updout, BN_, 256, 256, nullptr, nullptr, nullptr, nullptr, 0);
    ln_k<<<dim3(BN_ / 4), blk, 0, stream>>>(R_h, updout, 0, mp_ln_g, mp_ln_b, BN_);
    if (step == 2) {
      halt_k<<<dim3(32), blk, 0, stream>>>(R_h, halt_w, halt_b, R_hp);
      out2_k<<<dim3(BN_), blk, 0, stream>>>(R_h, R_hp, R_outp);
    } else if (step == 3) {
      out3_k<<<dim3(BN_), blk, 0, stream>>>(R_h, R_hp, R_outp);
    }
  }

  // ---- sparse retrieval attention ----
  float* qb = R_big;
  float* kb = R_big + SZ_Q;
  float* vb = R_big + 2 * SZ_Q;
  gemm_k<0, false, 0, 0><<<dim3(4, 256), blk, 0, stream>>>(
      R_outp, q_w, q_b, qb, BN_, 256, 256, nullptr, nullptr, nullptr, nullptr, 0);
  gemm_k<0, false, 0, 0><<<dim3(4, 256), blk, 0, stream>>>(
      R_outp, k_w, k_b, kb, BN_, 256, 256, nullptr, nullptr, nullptr, nullptr, 0);
  gemm_k<0, false, 0, 0><<<dim3(4, 256), blk, 0, stream>>>(
      R_outp, v_w, v_b, vb, BN_, 256, 256, nullptr, nullptr, nullptr, nullptr, 0);
  for (int half = 0; half < 2; ++half) {
    int b0 = half * 16;
    scores_k<<<dim3(8, 8, 16), blk, 0, stream>>>(qb, kb, R_sc, b0);
    topk_k<<<dim3(BN_ / 2), blk, 0, stream>>>(R_sc, vb, R_msgs, b0 * N_);
  }
  // retrieved = rpre @ o_w + o_b   (into kb region, dead now)
  float* retr  = kb;
  float* broad = R_h;               // h dead
  gemm_k<0, false, 0, 0><<<dim3(4, 256), blk, 0, stream>>>(
      R_msgs, o_w, o_b, retr, BN_, 256, 256, nullptr, nullptr, nullptr, nullptr, 0);
  gemm_k<5, false, 0, 0><<<dim3(4, 256), blk, 0, stream>>>(
      R_outp, br_w, br_b, broad, BN_, 256, 256, retr, nullptr, nullptr, nullptr, 0);

  // final = LN(local + broad[row/4]) in place (in d_out)
  ln_k<<<dim3(M1_ / 4), blk, 0, stream>>>(local, broad, 2, f_ln_g, f_ln_b, M1_);

  // logits = final @ head_w, chunked via scratch copy to avoid aliasing
  float* hscratch = R_big;          // qb region, dead
  constexpr int HC = 16384;
  for (int c = 0; c < M1_ / HC; ++c) {
    size_t ro = (size_t)c * HC;
    hipMemcpyAsync(hscratch, local + ro * 256, (size_t)HC * 256 * sizeof(float),
                   hipMemcpyDeviceToDevice, stream);
    gemm_k<0, false, 0, 0><<<dim3(4, HC / 64), blk, 0, stream>>>(
        hscratch, head_w, nullptr, logits + ro * 256, HC, 256, 256,
        nullptr, nullptr, nullptr, nullptr, 0);
  }

  // kl scalar
  kl_k<<<dim3(1), dim3(64), 0, stream>>>(R_hp, logits + (size_t)M1_ * 256);
}

// Round 3
// 2089.777 us; speedup vs baseline: 2.2112x; 2.2112x over previous
//
#include <hip/hip_runtime.h>
#include <cmath>

// ---------------------------------------------------------------------------
// SutraV04: patch-GRU + message passing + sparse retrieval LM block.
// B=32, T=2048, PS=4, D=256, N=512 patches/batch, BN=16384, V=256.
// Round 2: bf16 MFMA GEMMs (16x16x32), fp32 head, fixed halt reduction.
// ---------------------------------------------------------------------------

constexpr int N_   = 512;       // patches per batch
constexpr int B_   = 32;
constexpr int BN_  = B_ * N_;   // 16384
constexpr int M1_  = BN_ * 4;   // 65536

typedef short bf16x8 __attribute__((ext_vector_type(8)));
typedef float f32x4  __attribute__((ext_vector_type(4)));

__device__ __forceinline__ float gelu_f(float x) {
  return 0.5f * x * (1.0f + erff(x * 0.70710678118654752440f));
}
__device__ __forceinline__ float sigm_f(float x) {
  return 1.0f / (1.0f + expf(-x));
}
__device__ __forceinline__ unsigned short f2bf(float f) {
  union { float f; unsigned int u; } c; c.f = f;
  unsigned int u = c.u;
  u += 0x7FFFu + ((u >> 16) & 1u);
  return (unsigned short)(u >> 16);
}
// swizzled LDS index (shorts) for fragment-ordered tiles: [g][row^g][8]
__device__ __forceinline__ int phys(int g, int r) {
  return ((g << 6) | (r ^ g)) << 3;
}

// ---- A-operand gathers: 8 consecutive fp32 at [m][k..k+8) -----------------
// 0 plain; 1 GRU input emb[xi[m*4+t]]+pos[t]; 2 msg concat (t=kk);
// 3 upd concat (msgs/cnt); 4 patch mean; 5 A+P2
template<int MODE>
__device__ __forceinline__ void loadA8(float v[8], const float* __restrict__ A,
    const float* __restrict__ P2, const int* __restrict__ xi,
    const float* __restrict__ emb, const float* __restrict__ pos,
    int t, int m, int k, int K)
{
  if constexpr (MODE == 0) {
    const float4* p = (const float4*)(A + (size_t)m * K + k);
    float4 a = p[0], b = p[1];
    v[0]=a.x; v[1]=a.y; v[2]=a.z; v[3]=a.w; v[4]=b.x; v[5]=b.y; v[6]=b.z; v[7]=b.w;
  } else if constexpr (MODE == 1) {
    int tok = xi[m * 4 + t];
    const float4* pe = (const float4*)(emb + (size_t)tok * 256 + k);
    const float4* pp = (const float4*)(pos + (size_t)t * 256 + k);
    float4 a = pe[0], b = pe[1], c = pp[0], d = pp[1];
    v[0]=a.x+c.x; v[1]=a.y+c.y; v[2]=a.z+c.z; v[3]=a.w+c.w;
    v[4]=b.x+d.x; v[5]=b.y+d.y; v[6]=b.z+d.z; v[7]=b.w+d.w;
  } else if constexpr (MODE == 2) {
    const float* src;
    if (k < 256) src = A + (size_t)m * 256 + k;
    else {
      int n = m & (N_ - 1);
      int idx = n + t - 4; if (idx < 0) idx = 0;
      src = A + (size_t)(m - n + idx) * 256 + (k - 256);
    }
    const float4* p = (const float4*)src;
    float4 a = p[0], b = p[1];
    v[0]=a.x; v[1]=a.y; v[2]=a.z; v[3]=a.w; v[4]=b.x; v[5]=b.y; v[6]=b.z; v[7]=b.w;
  } else if constexpr (MODE == 3) {
    if (k < 256) {
      const float4* p = (const float4*)(A + (size_t)m * 256 + k);
      float4 a = p[0], b = p[1];
      v[0]=a.x; v[1]=a.y; v[2]=a.z; v[3]=a.w; v[4]=b.x; v[5]=b.y; v[6]=b.z; v[7]=b.w;
    } else {
      int n = m & (N_ - 1);
      float s = 1.0f / (float)((n < 4 ? n : 4) + 1);
      const float4* p = (const float4*)(P2 + (size_t)m * 256 + (k - 256));
      float4 a = p[0], b = p[1];
      v[0]=a.x*s; v[1]=a.y*s; v[2]=a.z*s; v[3]=a.w*s;
      v[4]=b.x*s; v[5]=b.y*s; v[6]=b.z*s; v[7]=b.w*s;
    }
  } else if constexpr (MODE == 4) {
    const float* base = A + (size_t)m * 1024 + k;
    #pragma unroll
    for (int h = 0; h < 2; ++h) {
      const float4* p0 = (const float4*)(base + h*4);
      const float4* p1 = (const float4*)(base + 256 + h*4);
      const float4* p2 = (const float4*)(base + 512 + h*4);
      const float4* p3 = (const float4*)(base + 768 + h*4);
      float4 a=p0[0], b=p1[0], c=p2[0], d=p3[0];
      v[h*4+0]=0.25f*(a.x+b.x+c.x+d.x); v[h*4+1]=0.25f*(a.y+b.y+c.y+d.y);
      v[h*4+2]=0.25f*(a.z+b.z+c.z+d.z); v[h*4+3]=0.25f*(a.w+b.w+c.w+d.w);
    }
  } else {
    const float4* p = (const float4*)(A  + (size_t)m * 256 + k);
    const float4* q = (const float4*)(P2 + (size_t)m * 256 + k);
    float4 a=p[0], b=p[1], c=q[0], d=q[1];
    v[0]=a.x+c.x; v[1]=a.y+c.y; v[2]=a.z+c.z; v[3]=a.w+c.w;
    v[4]=b.x+d.x; v[5]=b.y+d.y; v[6]=b.z+d.z; v[7]=b.w+d.w;
  }
}

// ---- MFMA GEMM: C[M,Nn] = epi(act(gatherA[M,K] @ Bt[Nn,K]^T + bias)) ------
// BSRC: 0 = Bt bf16 [Nn][K]; 1 = fp32 [Nn][K] (converted on stage).
// ACT: 0 none, 1 gelu.  EPI: 0 store; 1 masked += (t=kk); 2 scale+causal.
// Tile 64x64, K-step 32, 256 threads = 4 waves (2x2 of 32x32 each).
template<int MODE, int BSRC, int ACT, int EPI>
__global__ __launch_bounds__(256)
void gemm_mfma(const float* __restrict__ A, const void* __restrict__ Bsrc,
               const float* __restrict__ bias, float* __restrict__ C,
               int M, int Nn, int K,
               const float* __restrict__ P2, const int* __restrict__ xi,
               const float* __restrict__ emb, const float* __restrict__ pos,
               int t, size_t aStride, size_t bStride, size_t cStride)
{
  __shared__ short As[4 * 64 * 8];
  __shared__ short Bs[4 * 64 * 8];
  const int z = blockIdx.z;
  const float* Az = A ? (A + (size_t)z * aStride) : nullptr;
  float* Cz = C + (size_t)z * cStride;

  const int tid  = threadIdx.x;
  const int m0   = blockIdx.y * 64, n0 = blockIdx.x * 64;
  const int srow = tid >> 2, sg = tid & 3;       // staging: 4 thr/row
  const int lane = tid & 63, w = tid >> 6;
  const int wr   = w >> 1,  wc = w & 1;
  const int fr   = lane & 15, fg = lane >> 4;

  f32x4 acc[2][2] = {};

  for (int k0 = 0; k0 < K; k0 += 32) {
    // stage A (gather fp32 -> bf16)
    {
      float v[8];
      loadA8<MODE>(v, Az, P2, xi, emb, pos, t, m0 + srow, k0 + sg * 8, K);
      bf16x8 tv;
      #pragma unroll
      for (int j = 0; j < 8; ++j) tv[j] = (short)f2bf(v[j]);
      *(bf16x8*)&As[phys(sg, srow)] = tv;
    }
    // stage B
    if constexpr (BSRC == 0) {
      const unsigned short* Bt = (const unsigned short*)Bsrc;
      *(bf16x8*)&Bs[phys(sg, srow)] =
          *(const bf16x8*)&Bt[(size_t)(n0 + srow) * K + k0 + sg * 8];
    } else {
      const float* Bf = (const float*)Bsrc + (size_t)z * bStride;
      const float4* p = (const float4*)(Bf + (size_t)(n0 + srow) * K + k0 + sg * 8);
      float4 a = p[0], b = p[1];
      bf16x8 tv;
      tv[0]=(short)f2bf(a.x); tv[1]=(short)f2bf(a.y); tv[2]=(short)f2bf(a.z); tv[3]=(short)f2bf(a.w);
      tv[4]=(short)f2bf(b.x); tv[5]=(short)f2bf(b.y); tv[6]=(short)f2bf(b.z); tv[7]=(short)f2bf(b.w);
      *(bf16x8*)&Bs[phys(sg, srow)] = tv;
    }
    __syncthreads();

    bf16x8 a0 = *(const bf16x8*)&As[phys(fg, wr * 32 + fr)];
    bf16x8 a1 = *(const bf16x8*)&As[phys(fg, wr * 32 + 16 + fr)];
    bf16x8 b0 = *(const bf16x8*)&Bs[phys(fg, wc * 32 + fr)];
    bf16x8 b1 = *(const bf16x8*)&Bs[phys(fg, wc * 32 + 16 + fr)];
    acc[0][0] = __builtin_amdgcn_mfma_f32_16x16x32_bf16(a0, b0, acc[0][0], 0, 0, 0);
    acc[0][1] = __builtin_amdgcn_mfma_f32_16x16x32_bf16(a0, b1, acc[0][1], 0, 0, 0);
    acc[1][0] = __builtin_amdgcn_mfma_f32_16x16x32_bf16(a1, b0, acc[1][0], 0, 0, 0);
    acc[1][1] = __builtin_amdgcn_mfma_f32_16x16x32_bf16(a1, b1, acc[1][1], 0, 0, 0);
    __syncthreads();
  }

  #pragma unroll
  for (int i = 0; i < 2; ++i) {
    #pragma unroll
    for (int j = 0; j < 2; ++j) {
      int row0 = m0 + wr * 32 + i * 16 + fg * 4;
      int col  = n0 + wc * 32 + j * 16 + fr;
      float bcol = bias ? bias[col] : 0.0f;
      #pragma unroll
      for (int r = 0; r < 4; ++r) {
        float vv = acc[i][j][r] + bcol;
        if constexpr (ACT == 1) vv = gelu_f(vv);
        int row = row0 + r;
        if constexpr (EPI == 0) {
          Cz[(size_t)row * Nn + col] = vv;
        } else if constexpr (EPI == 1) {
          int n = row & (N_ - 1);
          if (n + t - 4 >= 0) Cz[(size_t)row * Nn + col] += vv;
        } else {
          vv *= 0.0625f;
          if (col > row) vv = -__builtin_inff();
          Cz[(size_t)row * Nn + col] = vv;
        }
      }
    }
  }
}

// ---- weight prep: bf16 transpose W[K,256] -> Bt[256][K] -------------------
struct PrepJobs {
  const float* src[10];
  unsigned short* dst[10];
  int logk[10];
};
__global__ __launch_bounds__(256)
void prep_w_k(PrepJobs pj)
{
  int jid = blockIdx.y;
  const float* src = pj.src[jid];
  unsigned short* dst = pj.dst[jid];
  int lk = pj.logk[jid];
  int total = 256 << lk, Km = (1 << lk) - 1;
  for (int i = blockIdx.x * 256 + threadIdx.x; i < total; i += gridDim.x * 256) {
    int k = i & Km, n = i >> lk;
    dst[i] = f2bf(src[(size_t)k * 256 + n]);
  }
}

// ---- GRU pointwise step ----------------------------------------------------
__global__ __launch_bounds__(256)
void gru_pw_k(const float* __restrict__ xg, const float* __restrict__ gh,
              float* __restrict__ h, float* __restrict__ local, int t)
{
  int i   = blockIdx.x * 256 + threadIdx.x;
  int row = i >> 8, d = i & 255;
  const float* xr = xg + (size_t)row * 768;
  const float* gr = gh + (size_t)row * 768;
  float ir = xr[d], iz = xr[256 + d], inn = xr[512 + d];
  float hr = gr[d], hz = gr[256 + d], hn  = gr[512 + d];
  float hprev = h[i];
  float r  = sigm_f(ir + hr);
  float zg = sigm_f(iz + hz);
  float nn = tanhf(inn + r * hn);
  float hnew = (1.0f - zg) * nn + zg * hprev;
  h[i] = hnew;
  local[((size_t)row * 4 + t) * 256 + d] = hnew;
}

// ---- LayerNorm (optionally Y = LN(X + Add[row>>shift])) in place ----------
__global__ __launch_bounds__(256)
void ln_k(float* __restrict__ X, const float* __restrict__ Add, int addShift,
          const float* __restrict__ g, const float* __restrict__ bb, int rows)
{
  int wave = threadIdx.x >> 6, lane = threadIdx.x & 63;
  int row  = blockIdx.x * 4 + wave;
  if (row >= rows) return;
  float* xr = X + (size_t)row * 256;
  float x[4];
  #pragma unroll
  for (int j = 0; j < 4; ++j) x[j] = xr[lane * 4 + j];
  if (Add) {
    const float* ar = Add + (size_t)(row >> addShift) * 256;
    #pragma unroll
    for (int j = 0; j < 4; ++j) x[j] += ar[lane * 4 + j];
  }
  float s = x[0] + x[1] + x[2] + x[3];
  #pragma unroll
  for (int off = 1; off < 64; off <<= 1) s += __shfl_xor(s, off, 64);
  float mean = s * (1.0f / 256.0f);
  float ss = 0.f;
  #pragma unroll
  for (int j = 0; j < 4; ++j) { float d = x[j] - mean; ss += d * d; }
  #pragma unroll
  for (int off = 1; off < 64; off <<= 1) ss += __shfl_xor(ss, off, 64);
  float inv = rsqrtf(ss * (1.0f / 256.0f) + 1e-5f);
  #pragma unroll
  for (int j = 0; j < 4; ++j)
    xr[lane * 4 + j] = (x[j] - mean) * inv * g[lane * 4 + j] + bb[lane * 4 + j];
}

// ---- halting probability: 2-stage deterministic reduction -----------------
__global__ __launch_bounds__(256)
void halt1_k(const float* __restrict__ h, const float* __restrict__ hw,
             float* __restrict__ part)
{
  int b = blockIdx.x, s = blockIdx.y, tid = threadIdx.x;
  const float* p = h + ((size_t)b * N_ + s * 32) * 256;
  float acc = 0.f;
  for (int i = tid; i < 32 * 256; i += 256) acc += p[i] * hw[i & 255];
  __shared__ float red[256];
  red[tid] = acc; __syncthreads();
  for (int off = 128; off > 0; off >>= 1) {
    if (tid < off) red[tid] += red[tid + off];
    __syncthreads();
  }
  if (tid == 0) part[b * 16 + s] = red[0];
}
__global__ __launch_bounds__(64)
void halt2_k(const float* __restrict__ part, const float* __restrict__ hb,
             float* __restrict__ hp)
{
  int b = threadIdx.x;
  if (b < 32) {
    float s = 0.f;
    for (int i = 0; i < 16; ++i) s += part[b * 16 + i];
    hp[b] = sigm_f(s * (1.0f / (float)N_) + hb[0]);
  }
}

__global__ __launch_bounds__(256)
void out2_k(const float* __restrict__ h, const float* __restrict__ hp,
            float* __restrict__ outp)
{
  int i = blockIdx.x * 256 + threadIdx.x;
  outp[i] = hp[i >> 17] * h[i];
}
__global__ __launch_bounds__(256)
void out3_k(const float* __restrict__ h, const float* __restrict__ hp,
            float* __restrict__ outp)
{
  int i = blockIdx.x * 256 + threadIdx.x;
  outp[i] += (1.0f - hp[i >> 17]) * h[i];
}

// ---- per-row top-8 + softmax + weighted V gather --------------------------
__global__ __launch_bounds__(256)
void topk_k(const float* __restrict__ s, const float* __restrict__ v,
            float* __restrict__ rpre, int r0)
{
  int rowg = r0 + blockIdx.x;
  int b = rowg >> 9;
  const float* srow = s + (size_t)blockIdx.x * N_;
  __shared__ float sv[512];
  __shared__ float redV[256];
  __shared__ int   redI[256];
  __shared__ float topv[8];
  __shared__ int   topi[8];
  __shared__ float wsh[8];
  int tid = threadIdx.x;
  sv[tid] = srow[tid];
  sv[tid + 256] = srow[tid + 256];
  __syncthreads();
  for (int it = 0; it < 8; ++it) {
    float v0 = sv[tid], v1 = sv[tid + 256];
    float bv; int bi;
    if (v1 > v0) { bv = v1; bi = tid + 256; } else { bv = v0; bi = tid; }
    redV[tid] = bv; redI[tid] = bi;
    __syncthreads();
    for (int off = 128; off > 0; off >>= 1) {
      if (tid < off) {
        float ov = redV[tid + off]; int oi = redI[tid + off];
        if (ov > redV[tid] || (ov == redV[tid] && oi < redI[tid])) {
          redV[tid] = ov; redI[tid] = oi;
        }
      }
      __syncthreads();
    }
    if (tid == 0) {
      topv[it] = redV[0]; topi[it] = redI[0];
      sv[redI[0]] = -__builtin_inff();
    }
    __syncthreads();
  }
  if (tid == 0) {
    float mx = topv[0];
    float ssum = 0.f;
    for (int j = 0; j < 8; ++j) { float e = expf(topv[j] - mx); wsh[j] = e; ssum += e; }
    float inv = 1.0f / ssum;
    for (int j = 0; j < 8; ++j) wsh[j] *= inv;
  }
  __syncthreads();
  float acc = 0.f;
  #pragma unroll
  for (int j = 0; j < 8; ++j)
    acc += wsh[j] * v[((size_t)(b * N_ + topi[j])) * 256 + tid];
  rpre[(size_t)rowg * 256 + tid] = acc;
}

// ---- fp32 head GEMM (64x64 tile SIMD) -------------------------------------
__global__ __launch_bounds__(256)
void head_k(const float* __restrict__ A, const float* __restrict__ Bm,
            float* __restrict__ C, int M)
{
  __shared__ float As[16][64];
  __shared__ float Bs[16][64];
  const int tid = threadIdx.x;
  const int tx = tid & 15, ty = tid >> 4;
  const int m0 = blockIdx.y * 64, n0 = blockIdx.x * 64;
  float acc[4][4] = {};
  for (int k0 = 0; k0 < 256; k0 += 16) {
    {
      int l = tid * 4;
      int ml = l >> 4, kl = l & 15;
      #pragma unroll
      for (int j = 0; j < 4; ++j)
        As[kl + j][ml] = A[(size_t)(m0 + ml) * 256 + k0 + kl + j];
    }
    {
      int l = tid * 4;
      int kl = l >> 6, nl = l & 63;
      #pragma unroll
      for (int j = 0; j < 4; ++j)
        Bs[kl][nl + j] = Bm[(size_t)(k0 + kl) * 256 + (n0 + nl + j)];
    }
    __syncthreads();
    #pragma unroll
    for (int kk = 0; kk < 16; ++kk) {
      float a[4], b[4];
      #pragma unroll
      for (int r = 0; r < 4; ++r) a[r] = As[kk][ty * 4 + r];
      #pragma unroll
      for (int c = 0; c < 4; ++c) b[c] = Bs[kk][tx * 4 + c];
      #pragma unroll
      for (int r = 0; r < 4; ++r)
        #pragma unroll
        for (int c = 0; c < 4; ++c)
          acc[r][c] += a[r] * b[c];
    }
    __syncthreads();
  }
  #pragma unroll
  for (int r = 0; r < 4; ++r) {
    int row = m0 + ty * 4 + r;
    #pragma unroll
    for (int c = 0; c < 4; ++c)
      C[(size_t)row * 256 + n0 + tx * 4 + c] = acc[r][c];
  }
}

// ---- KL scalar -------------------------------------------------------------
__global__ void kl_k(const float* __restrict__ hp, float* __restrict__ out)
{
  if (threadIdx.x == 0 && blockIdx.x == 0) {
    float hm = 0.f;
    for (int b = 0; b < 32; ++b) hm += hp[b];
    hm *= (1.0f / 32.0f);
    const float l1e8 = logf(1e-8f);
    float kl = 0.f;
    kl += 0.2f    * (logf(0.2f)    - l1e8);
    kl += 0.16f   * (logf(0.16f)   - l1e8);
    kl += 0.128f  * (logf(0.128f)  - logf(hm + 1e-8f));
    kl += 0.1024f * (logf(0.1024f) - logf(1.0f + 1e-8f));
    out[0] = kl * 0.25f;
  }
}

// ---------------------------------------------------------------------------
extern "C" void kernel_launch(void* const* d_in, const int* in_sizes, int n_in,
                              void* d_out, int out_size, void* d_ws, size_t ws_size,
                              hipStream_t stream)
{
  const int*   x       = (const int*)  d_in[0];
  const float* emb     = (const float*)d_in[1];
  const float* pos     = (const float*)d_in[2];
  const float* gru_wih = (const float*)d_in[3];
  const float* gru_whh = (const float*)d_in[4];
  const float* gru_bih = (const float*)d_in[5];
  const float* gru_bhh = (const float*)d_in[6];
  const float* pp_ln_g = (const float*)d_in[7];
  const float* pp_ln_b = (const float*)d_in[8];
  const float* sum_w   = (const float*)d_in[9];
  const float* sum_b   = (const float*)d_in[10];
  const float* msg_w1  = (const float*)d_in[11];
  const float* msg_b1  = (const float*)d_in[12];
  const float* msg_w2  = (const float*)d_in[13];
  const float* msg_b2  = (const float*)d_in[14];
  const float* upd_w1  = (const float*)d_in[15];
  const float* upd_b1  = (const float*)d_in[16];
  const float* upd_w2  = (const float*)d_in[17];
  const float* upd_b2  = (const float*)d_in[18];
  const float* halt_w  = (const float*)d_in[19];
  const float* halt_b  = (const float*)d_in[20];
  const float* mp_ln_g = (const float*)d_in[21];
  const float* mp_ln_b = (const float*)d_in[22];
  const float* q_w     = (const float*)d_in[23];
  const float* q_b     = (const float*)d_in[24];
  const float* k_w     = (const float*)d_in[25];
  const float* k_b     = (const float*)d_in[26];
  const float* v_w     = (const float*)d_in[27];
  const float* v_b     = (const float*)d_in[28];
  const float* o_w     = (const float*)d_in[29];
  const float* o_b     = (const float*)d_in[30];
  const float* br_w    = (const float*)d_in[31];
  const float* br_b    = (const float*)d_in[32];
  const float* f_ln_g  = (const float*)d_in[33];
  const float* f_ln_b  = (const float*)d_in[34];
  const float* head_w  = (const float*)d_in[35];

  // ---- workspace layout (floats), ~102 MB ----
  constexpr size_t SZ_Q   = (size_t)BN_ * 256;   // 4,194,304 (16.78 MB)
  constexpr size_t SZ_BIG = 3 * SZ_Q;            // 50.33 MB
  float* ws     = (float*)d_ws;
  float* R_h    = ws;                   // also: scores half-buffer, broad
  float* R_outp = R_h    + SZ_Q;
  float* R_msgs = R_outp + SZ_Q;        // also: rpre
  float* R_big  = R_msgs + SZ_Q;        // xg/gh chunks; qb/kb/vb; head scratch
  unsigned short* wb = (unsigned short*)(R_big + SZ_BIG);
  unsigned short* sumT = wb;                    // [256][256]
  unsigned short* m1T  = sumT + 65536;          // [256][512]
  unsigned short* m2T  = m1T  + 131072;         // [256][256]
  unsigned short* u1T  = m2T  + 65536;          // [256][512]
  unsigned short* u2T  = u1T  + 131072;
  unsigned short* qT   = u2T  + 65536;
  unsigned short* kT   = qT   + 65536;
  unsigned short* vT   = kT   + 65536;
  unsigned short* oT   = vT   + 65536;
  unsigned short* brT  = oT   + 65536;
  float* R_part = (float*)(brT + 65536);
  float* R_hp   = R_part + 512;

  float* local  = (float*)d_out;        // 16,777,216 floats
  float* logits = (float*)d_out;

  dim3 blk(256);

  // ---- weight prep (bf16 transposes) ----
  PrepJobs pj;
  const float* srcs[10] = {sum_w, msg_w1, msg_w2, upd_w1, upd_w2, q_w, k_w, v_w, o_w, br_w};
  unsigned short* dsts[10] = {sumT, m1T, m2T, u1T, u2T, qT, kT, vT, oT, brT};
  int lks[10] = {8, 9, 8, 9, 8, 8, 8, 8, 8, 8};
  for (int i = 0; i < 10; ++i) { pj.src[i]=srcs[i]; pj.dst[i]=dsts[i]; pj.logk[i]=lks[i]; }
  prep_w_k<<<dim3(256, 10), blk, 0, stream>>>(pj);

  // ---- patch GRU (4 steps, 4 row-chunks of 4096) ----
  constexpr int CH = 4096;
  hipMemsetAsync(R_h, 0, SZ_Q * sizeof(float), stream);
  float* xgc = R_big;
  float* ghc = R_big + (size_t)CH * 768;
  for (int t = 0; t < 4; ++t) {
    for (int c = 0; c < BN_ / CH; ++c) {
      size_t ro = (size_t)c * CH;
      gemm_mfma<1, 1, 0, 0><<<dim3(12, CH / 64), blk, 0, stream>>>(
          nullptr, gru_wih, gru_bih, xgc, CH, 768, 256,
          nullptr, x + ro * 4, emb, pos, t, 0, 0, 0);
      gemm_mfma<0, 1, 0, 0><<<dim3(12, CH / 64), blk, 0, stream>>>(
          R_h + ro * 256, gru_whh, gru_bhh, ghc, CH, 768, 256,
          nullptr, nullptr, nullptr, nullptr, 0, 0, 0, 0);
      gru_pw_k<<<dim3(CH), blk, 0, stream>>>(
          xgc, ghc, R_h + ro * 256, local + ro * 1024, t);
    }
  }
  ln_k<<<dim3(M1_ / 4), blk, 0, stream>>>(local, nullptr, 0, pp_ln_g, pp_ln_b, M1_);

  // summaries -> h
  gemm_mfma<4, 0, 0, 0><<<dim3(4, 256), blk, 0, stream>>>(
      local, sumT, sum_b, R_h, BN_, 256, 256,
      nullptr, nullptr, nullptr, nullptr, 0, 0, 0, 0);

  // ---- message-passing rounds ----
  float* hid    = R_big;
  float* updout = R_big + SZ_Q;
  for (int step = 0; step < 4; ++step) {
    hipMemsetAsync(R_msgs, 0, SZ_Q * sizeof(float), stream);
    for (int kk = 0; kk < 5; ++kk) {
      gemm_mfma<2, 0, 1, 0><<<dim3(4, 256), blk, 0, stream>>>(
          R_h, m1T, msg_b1, hid, BN_, 256, 512,
          nullptr, nullptr, nullptr, nullptr, kk, 0, 0, 0);
      gemm_mfma<0, 0, 0, 1><<<dim3(4, 256), blk, 0, stream>>>(
          hid, m2T, msg_b2, R_msgs, BN_, 256, 256,
          nullptr, nullptr, nullptr, nullptr, kk, 0, 0, 0);
    }
    gemm_mfma<3, 0, 1, 0><<<dim3(4, 256), blk, 0, stream>>>(
        R_h, u1T, upd_b1, hid, BN_, 256, 512,
        R_msgs, nullptr, nullptr, nullptr, 0, 0, 0, 0);
    gemm_mfma<0, 0, 0, 0><<<dim3(4, 256), blk, 0, stream>>>(
        hid, u2T, upd_b2, updout, BN_, 256, 256,
        nullptr, nullptr, nullptr, nullptr, 0, 0, 0, 0);
    ln_k<<<dim3(BN_ / 4), blk, 0, stream>>>(R_h, updout, 0, mp_ln_g, mp_ln_b, BN_);
    if (step == 2) {
      halt1_k<<<dim3(32, 16), blk, 0, stream>>>(R_h, halt_w, R_part);
      halt2_k<<<dim3(1), dim3(64), 0, stream>>>(R_part, halt_b, R_hp);
      out2_k<<<dim3(BN_), blk, 0, stream>>>(R_h, R_hp, R_outp);
    } else if (step == 3) {
      out3_k<<<dim3(BN_), blk, 0, stream>>>(R_h, R_hp, R_outp);
    }
  }

  // ---- sparse retrieval attention ----
  float* qb = R_big;
  float* kb = R_big + SZ_Q;
  float* vb = R_big + 2 * SZ_Q;
  float* sc = R_h;                       // h dead; 16x512x512 fits exactly
  gemm_mfma<0, 0, 0, 0><<<dim3(4, 256), blk, 0, stream>>>(
      R_outp, qT, q_b, qb, BN_, 256, 256,
      nullptr, nullptr, nullptr, nullptr, 0, 0, 0, 0);
  gemm_mfma<0, 0, 0, 0><<<dim3(4, 256), blk, 0, stream>>>(
      R_outp, kT, k_b, kb, BN_, 256, 256,
      nullptr, nullptr, nullptr, nullptr, 0, 0, 0, 0);
  gemm_mfma<0, 0, 0, 0><<<dim3(4, 256), blk, 0, stream>>>(
      R_outp, vT, v_b, vb, BN_, 256, 256,
      nullptr, nullptr, nullptr, nullptr, 0, 0, 0, 0);
  for (int half = 0; half < 2; ++half) {
    size_t bo = (size_t)half * 16 * N_ * 256;
    gemm_mfma<0, 1, 0, 2><<<dim3(8, 8, 16), blk, 0, stream>>>(
        qb + bo, kb + bo, nullptr, sc, N_, N_, 256,
        nullptr, nullptr, nullptr, nullptr, 0,
        (size_t)N_ * 256, (size_t)N_ * 256, (size_t)N_ * N_);
    topk_k<<<dim3(BN_ / 2), blk, 0, stream>>>(sc, vb, R_msgs, half * 16 * N_);
  }
  float* retr  = kb;
  float* broad = R_h;
  gemm_mfma<0, 0, 0, 0><<<dim3(4, 256), blk, 0, stream>>>(
      R_msgs, oT, o_b, retr, BN_, 256, 256,
      nullptr, nullptr, nullptr, nullptr, 0, 0, 0, 0);
  gemm_mfma<5, 0, 0, 0><<<dim3(4, 256), blk, 0, stream>>>(
      R_outp, brT, br_b, broad, BN_, 256, 256,
      retr, nullptr, nullptr, nullptr, 0, 0, 0, 0);

  // final = LN(local + broad[row/4]) in place (in d_out)
  ln_k<<<dim3(M1_ / 4), blk, 0, stream>>>(local, broad, 2, f_ln_g, f_ln_b, M1_);

  // logits = final @ head_w (fp32), chunked via scratch to avoid aliasing
  float* hscratch = R_big;
  constexpr int HC = 16384;
  for (int c = 0; c < M1_ / HC; ++c) {
    size_t ro = (size_t)c * HC;
    hipMemcpyAsync(hscratch, local + ro * 256, (size_t)HC * 256 * sizeof(float),
                   hipMemcpyDeviceToDevice, stream);
    head_k<<<dim3(4, HC / 64), blk, 0, stream>>>(
        hscratch, head_w, logits + ro * 256, HC);
  }

  // kl scalar
  kl_k<<<dim3(1), dim3(64), 0, stream>>>(R_hp, logits + (size_t)M1_ * 256);
}

// Round 4
// 945.651 us; speedup vs baseline: 4.8864x; 2.2099x over previous
//
#include <hip/hip_runtime.h>
#include <cmath>

// ---------------------------------------------------------------------------
// SutraV04 round 3: algebraic flop reduction.
//  - msg MLP factored: hsn = h@[W1a|W1b] once; S = sum of gelus (pointwise);
//    msgs path collapsed into T=S@W2, P=rowscale(T@U1b), U=gelu(h@U1a+P+biasU)
//  - GRU input GEMM replaced by embW table gather (V=256)
//  - head GEMM in bf16 MFMA with fused LN+convert
//  - topk: wave-per-row shfl butterfly argmax
// ---------------------------------------------------------------------------

constexpr int N_   = 512;
constexpr int B_   = 32;
constexpr int BN_  = B_ * N_;   // 16384
constexpr int M1_  = BN_ * 4;   // 65536

typedef short bf16x8 __attribute__((ext_vector_type(8)));
typedef float f32x4  __attribute__((ext_vector_type(4)));

__device__ __forceinline__ float gelu_f(float x) {
  return 0.5f * x * (1.0f + erff(x * 0.70710678118654752440f));
}
__device__ __forceinline__ float sigm_f(float x) {
  return 1.0f / (1.0f + expf(-x));
}
__device__ __forceinline__ unsigned short f2bf(float f) {
  union { float f; unsigned int u; } c; c.f = f;
  unsigned int u = c.u;
  u += 0x7FFFu + ((u >> 16) & 1u);
  return (unsigned short)(u >> 16);
}
__device__ __forceinline__ int phys(int g, int r) {
  return ((g << 6) | (r ^ g)) << 3;
}

// ---- A gathers (8 fp32 at [m][k..k+8)) ------------------------------------
// 0 plain fp32 [m][K]; 4 patch mean; 5 A+P2; 6 emb/pos table rows
template<int MODE>
__device__ __forceinline__ void loadA8(float v[8], const float* __restrict__ A,
    const float* __restrict__ P2, const float* __restrict__ emb,
    const float* __restrict__ pos, int m, int k, int K)
{
  if constexpr (MODE == 0) {
    const float4* p = (const float4*)(A + (size_t)m * K + k);
    float4 a = p[0], b = p[1];
    v[0]=a.x; v[1]=a.y; v[2]=a.z; v[3]=a.w; v[4]=b.x; v[5]=b.y; v[6]=b.z; v[7]=b.w;
  } else if constexpr (MODE == 4) {
    const float* base = A + (size_t)m * 1024 + k;
    #pragma unroll
    for (int h = 0; h < 2; ++h) {
      const float4* p0 = (const float4*)(base + h*4);
      const float4* p1 = (const float4*)(base + 256 + h*4);
      const float4* p2 = (const float4*)(base + 512 + h*4);
      const float4* p3 = (const float4*)(base + 768 + h*4);
      float4 a=p0[0], b=p1[0], c=p2[0], d=p3[0];
      v[h*4+0]=0.25f*(a.x+b.x+c.x+d.x); v[h*4+1]=0.25f*(a.y+b.y+c.y+d.y);
      v[h*4+2]=0.25f*(a.z+b.z+c.z+d.z); v[h*4+3]=0.25f*(a.w+b.w+c.w+d.w);
    }
  } else if constexpr (MODE == 5) {
    const float4* p = (const float4*)(A  + (size_t)m * 256 + k);
    const float4* q = (const float4*)(P2 + (size_t)m * 256 + k);
    float4 a=p[0], b=p[1], c=q[0], d=q[1];
    v[0]=a.x+c.x; v[1]=a.y+c.y; v[2]=a.z+c.z; v[3]=a.w+c.w;
    v[4]=b.x+d.x; v[5]=b.y+d.y; v[6]=b.z+d.z; v[7]=b.w+d.w;
  } else { // 6: emb rows then pos rows
    const float* src = nullptr;
    if (m < 256) src = emb + (size_t)m * 256 + k;
    else if (m < 260) src = pos + (size_t)(m - 256) * 256 + k;
    if (src) {
      const float4* p = (const float4*)src;
      float4 a = p[0], b = p[1];
      v[0]=a.x; v[1]=a.y; v[2]=a.z; v[3]=a.w; v[4]=b.x; v[5]=b.y; v[6]=b.z; v[7]=b.w;
    } else {
      #pragma unroll
      for (int j = 0; j < 8; ++j) v[j] = 0.f;
    }
  }
}

// ---- MFMA GEMM: C[M,Nn] = epi(gatherA[M,K] @ B[Nn,K]^T + bias) ------------
// MODE: A gather (0/4/5/6; 7 = A is bf16 [m][K]).
// BSRC: 0 bf16 Bt[n][bstride]; 1 fp32 Bt[n][bstride].
// EPI: 0 store; 2 scale 1/16 + causal; 3 rowscale 1/cnt(n); 4 gelu(v+P2).
template<int MODE, int BSRC, int EPI>
__global__ __launch_bounds__(256)
void gemm_mfma(const float* __restrict__ A, const void* __restrict__ Bsrc,
               const float* __restrict__ bias, float* __restrict__ C,
               int M, int Nn, int K, int bstride,
               const float* __restrict__ P2,
               const float* __restrict__ emb, const float* __restrict__ pos,
               size_t aStride, size_t bStride, size_t cStride)
{
  __shared__ short As[4 * 64 * 8];
  __shared__ short Bs[4 * 64 * 8];
  const int z = blockIdx.z;
  const float* Az = A ? (A + (size_t)z * aStride) : nullptr;
  float* Cz = C + (size_t)z * cStride;

  const int tid  = threadIdx.x;
  const int m0   = blockIdx.y * 64, n0 = blockIdx.x * 64;
  const int srow = tid >> 2, sg = tid & 3;
  const int lane = tid & 63, w = tid >> 6;
  const int wr   = w >> 1,  wc = w & 1;
  const int fr   = lane & 15, fg = lane >> 4;

  f32x4 acc[2][2] = {};

  for (int k0 = 0; k0 < K; k0 += 32) {
    if constexpr (MODE == 7) {
      const unsigned short* Ab = (const unsigned short*)Az;
      *(bf16x8*)&As[phys(sg, srow)] =
          *(const bf16x8*)&Ab[(size_t)(m0 + srow) * K + k0 + sg * 8];
    } else {
      float v[8];
      loadA8<MODE>(v, Az, P2, emb, pos, m0 + srow, k0 + sg * 8, K);
      bf16x8 tv;
      #pragma unroll
      for (int j = 0; j < 8; ++j) tv[j] = (short)f2bf(v[j]);
      *(bf16x8*)&As[phys(sg, srow)] = tv;
    }
    if constexpr (BSRC == 0) {
      const unsigned short* Bt = (const unsigned short*)Bsrc;
      *(bf16x8*)&Bs[phys(sg, srow)] =
          *(const bf16x8*)&Bt[(size_t)(n0 + srow) * bstride + k0 + sg * 8];
    } else {
      const float* Bf = (const float*)Bsrc + (size_t)z * bStride;
      const float4* p = (const float4*)(Bf + (size_t)(n0 + srow) * bstride + k0 + sg * 8);
      float4 a = p[0], b = p[1];
      bf16x8 tv;
      tv[0]=(short)f2bf(a.x); tv[1]=(short)f2bf(a.y); tv[2]=(short)f2bf(a.z); tv[3]=(short)f2bf(a.w);
      tv[4]=(short)f2bf(b.x); tv[5]=(short)f2bf(b.y); tv[6]=(short)f2bf(b.z); tv[7]=(short)f2bf(b.w);
      *(bf16x8*)&Bs[phys(sg, srow)] = tv;
    }
    __syncthreads();

    bf16x8 a0 = *(const bf16x8*)&As[phys(fg, wr * 32 + fr)];
    bf16x8 a1 = *(const bf16x8*)&As[phys(fg, wr * 32 + 16 + fr)];
    bf16x8 b0 = *(const bf16x8*)&Bs[phys(fg, wc * 32 + fr)];
    bf16x8 b1 = *(const bf16x8*)&Bs[phys(fg, wc * 32 + 16 + fr)];
    acc[0][0] = __builtin_amdgcn_mfma_f32_16x16x32_bf16(a0, b0, acc[0][0], 0, 0, 0);
    acc[0][1] = __builtin_amdgcn_mfma_f32_16x16x32_bf16(a0, b1, acc[0][1], 0, 0, 0);
    acc[1][0] = __builtin_amdgcn_mfma_f32_16x16x32_bf16(a1, b0, acc[1][0], 0, 0, 0);
    acc[1][1] = __builtin_amdgcn_mfma_f32_16x16x32_bf16(a1, b1, acc[1][1], 0, 0, 0);
    __syncthreads();
  }

  #pragma unroll
  for (int i = 0; i < 2; ++i) {
    #pragma unroll
    for (int j = 0; j < 2; ++j) {
      int row0 = m0 + wr * 32 + i * 16 + fg * 4;
      int col  = n0 + wc * 32 + j * 16 + fr;
      float bcol = bias ? bias[col] : 0.0f;
      #pragma unroll
      for (int r = 0; r < 4; ++r) {
        float vv = acc[i][j][r] + bcol;
        int row = row0 + r;
        if constexpr (EPI == 0) {
          Cz[(size_t)row * Nn + col] = vv;
        } else if constexpr (EPI == 2) {
          vv *= 0.0625f;
          if (col > row) vv = -__builtin_inff();
          Cz[(size_t)row * Nn + col] = vv;
        } else if constexpr (EPI == 3) {
          int n = row & (N_ - 1);
          vv *= 1.0f / (float)((n < 4 ? n : 4) + 1);
          Cz[(size_t)row * Nn + col] = vv;
        } else { // 4
          vv = gelu_f(vv + P2[(size_t)row * Nn + col]);
          Cz[(size_t)row * Nn + col] = vv;
        }
      }
    }
  }
}

// ---- weight prep: bf16 cast, optionally transposed ------------------------
struct PrepJobs {
  const float* src[16];
  unsigned short* dst[16];
  int rows[16];     // output rows n
  int strt[16];     // 1 = straight cast, 0 = transpose (src[k*256+n])
};
__global__ __launch_bounds__(256)
void prep_w_k(PrepJobs pj)
{
  int jid = blockIdx.y;
  const float* src = pj.src[jid];
  unsigned short* dst = pj.dst[jid];
  int total = pj.rows[jid] << 8;
  if (pj.strt[jid]) {
    for (int i = blockIdx.x * 256 + threadIdx.x; i < total; i += gridDim.x * 256)
      dst[i] = f2bf(src[i]);
  } else {
    for (int i = blockIdx.x * 256 + threadIdx.x; i < total; i += gridDim.x * 256) {
      int k = i & 255, n = i >> 8;
      dst[i] = f2bf(src[(size_t)k * 256 + n]);
    }
  }
}

// ---- bias prep: biasU = upd_b1 + msg_b2 @ upd_w1[256:]; biasHsn -----------
__global__ __launch_bounds__(256)
void biasprep_k(const float* __restrict__ upd_b1, const float* __restrict__ msg_b2,
                const float* __restrict__ upd_w1, const float* __restrict__ msg_b1,
                float* __restrict__ biasU, float* __restrict__ biasHsn)
{
  int c = threadIdx.x;
  float s = upd_b1[c];
  for (int k = 0; k < 256; ++k)
    s += msg_b2[k] * upd_w1[(size_t)(256 + k) * 256 + c];
  biasU[c] = s;
  biasHsn[c] = msg_b1[c];
  biasHsn[256 + c] = 0.f;
}

// ---- GRU pointwise (xg gathered from embW/posW tables) --------------------
__global__ __launch_bounds__(256)
void gru_pw_k(const float* __restrict__ gh, const float* __restrict__ embW,
              const int* __restrict__ x, const float* __restrict__ bih,
              float* __restrict__ h, float* __restrict__ local, int t)
{
  int i   = blockIdx.x * 256 + threadIdx.x;
  int row = i >> 8, d = i & 255;
  int tok = x[row * 4 + t];
  const float* er = embW + (size_t)tok * 768;
  const float* pr = embW + (size_t)(256 + t) * 768;
  float ir  = er[d]       + pr[d]       + bih[d];
  float iz  = er[256 + d] + pr[256 + d] + bih[256 + d];
  float inn = er[512 + d] + pr[512 + d] + bih[512 + d];
  const float* gr = gh + (size_t)row * 768;
  float hr = gr[d], hz = gr[256 + d], hn = gr[512 + d];
  float hprev = h[i];
  float r  = sigm_f(ir + hr);
  float zg = sigm_f(iz + hz);
  float nn = tanhf(inn + r * hn);
  float hnew = (1.0f - zg) * nn + zg * hprev;
  h[i] = hnew;
  local[((size_t)row * 4 + t) * 256 + d] = hnew;
}

// ---- S = sum over valid kk of gelu(hs + shifted hn) -----------------------
__global__ __launch_bounds__(256)
void smsg_k(const float* __restrict__ hsn, float* __restrict__ S)
{
  int i = blockIdx.x * 256 + threadIdx.x;   // BN*64
  int m = i >> 6, d4 = (i & 63) << 2;
  int n = m & (N_ - 1);
  const float4 hs = *(const float4*)&hsn[(size_t)m * 512 + d4];
  float4 acc = {0.f, 0.f, 0.f, 0.f};
  #pragma unroll
  for (int kk = 0; kk < 5; ++kk) {
    int idx = n + kk - 4;
    if (idx >= 0) {
      float4 hv = *(const float4*)&hsn[(size_t)(m + kk - 4) * 512 + 256 + d4];
      acc.x += gelu_f(hs.x + hv.x);
      acc.y += gelu_f(hs.y + hv.y);
      acc.z += gelu_f(hs.z + hv.z);
      acc.w += gelu_f(hs.w + hv.w);
    }
  }
  *(float4*)&S[(size_t)m * 256 + d4] = acc;
}

// ---- LayerNorm in place (optional add) ------------------------------------
__global__ __launch_bounds__(256)
void ln_k(float* __restrict__ X, const float* __restrict__ Add, int addShift,
          const float* __restrict__ g, const float* __restrict__ bb, int rows)
{
  int wave = threadIdx.x >> 6, lane = threadIdx.x & 63;
  int row  = blockIdx.x * 4 + wave;
  if (row >= rows) return;
  float* xr = X + (size_t)row * 256;
  float x[4];
  #pragma unroll
  for (int j = 0; j < 4; ++j) x[j] = xr[lane * 4 + j];
  if (Add) {
    const float* ar = Add + (size_t)(row >> addShift) * 256;
    #pragma unroll
    for (int j = 0; j < 4; ++j) x[j] += ar[lane * 4 + j];
  }
  float s = x[0] + x[1] + x[2] + x[3];
  #pragma unroll
  for (int off = 1; off < 64; off <<= 1) s += __shfl_xor(s, off, 64);
  float mean = s * (1.0f / 256.0f);
  float ss = 0.f;
  #pragma unroll
  for (int j = 0; j < 4; ++j) { float d = x[j] - mean; ss += d * d; }
  #pragma unroll
  for (int off = 1; off < 64; off <<= 1) ss += __shfl_xor(ss, off, 64);
  float inv = rsqrtf(ss * (1.0f / 256.0f) + 1e-5f);
  #pragma unroll
  for (int j = 0; j < 4; ++j)
    xr[lane * 4 + j] = (x[j] - mean) * inv * g[lane * 4 + j] + bb[lane * 4 + j];
}

// ---- final LN + bf16 convert (reads local+broad, writes bf16 A) -----------
__global__ __launch_bounds__(256)
void ln_cvt_k(const float* __restrict__ X, const float* __restrict__ Add,
              const float* __restrict__ g, const float* __restrict__ bb,
              unsigned short* __restrict__ Out)
{
  int wave = threadIdx.x >> 6, lane = threadIdx.x & 63;
  int row  = blockIdx.x * 4 + wave;
  const float* xr = X + (size_t)row * 256;
  const float* ar = Add + (size_t)(row >> 2) * 256;
  float x[4];
  #pragma unroll
  for (int j = 0; j < 4; ++j) x[j] = xr[lane * 4 + j] + ar[lane * 4 + j];
  float s = x[0] + x[1] + x[2] + x[3];
  #pragma unroll
  for (int off = 1; off < 64; off <<= 1) s += __shfl_xor(s, off, 64);
  float mean = s * (1.0f / 256.0f);
  float ss = 0.f;
  #pragma unroll
  for (int j = 0; j < 4; ++j) { float d = x[j] - mean; ss += d * d; }
  #pragma unroll
  for (int off = 1; off < 64; off <<= 1) ss += __shfl_xor(ss, off, 64);
  float inv = rsqrtf(ss * (1.0f / 256.0f) + 1e-5f);
  ushort4 o;
  o.x = f2bf((x[0] - mean) * inv * g[lane*4+0] + bb[lane*4+0]);
  o.y = f2bf((x[1] - mean) * inv * g[lane*4+1] + bb[lane*4+1]);
  o.z = f2bf((x[2] - mean) * inv * g[lane*4+2] + bb[lane*4+2]);
  o.w = f2bf((x[3] - mean) * inv * g[lane*4+3] + bb[lane*4+3]);
  *(ushort4*)&Out[(size_t)row * 256 + lane * 4] = o;
}

// ---- halting: 2-stage reduction -------------------------------------------
__global__ __launch_bounds__(256)
void halt1_k(const float* __restrict__ h, const float* __restrict__ hw,
             float* __restrict__ part)
{
  int b = blockIdx.x, s = blockIdx.y, tid = threadIdx.x;
  const float* p = h + ((size_t)b * N_ + s * 32) * 256;
  float acc = 0.f;
  for (int i = tid; i < 32 * 256; i += 256) acc += p[i] * hw[i & 255];
  __shared__ float red[256];
  red[tid] = acc; __syncthreads();
  for (int off = 128; off > 0; off >>= 1) {
    if (tid < off) red[tid] += red[tid + off];
    __syncthreads();
  }
  if (tid == 0) part[b * 16 + s] = red[0];
}
__global__ __launch_bounds__(64)
void halt2_k(const float* __restrict__ part, const float* __restrict__ hb,
             float* __restrict__ hp)
{
  int b = threadIdx.x;
  if (b < 32) {
    float s = 0.f;
    for (int i = 0; i < 16; ++i) s += part[b * 16 + i];
    hp[b] = sigm_f(s * (1.0f / (float)N_) + hb[0]);
  }
}

__global__ __launch_bounds__(256)
void out2_k(const float* __restrict__ h, const float* __restrict__ hp,
            float* __restrict__ outp)
{
  int i = blockIdx.x * 256 + threadIdx.x;
  outp[i] = hp[i >> 17] * h[i];
}
__global__ __launch_bounds__(256)
void out3_k(const float* __restrict__ h, const float* __restrict__ hp,
            float* __restrict__ outp)
{
  int i = blockIdx.x * 256 + threadIdx.x;
  outp[i] += (1.0f - hp[i >> 17]) * h[i];
}

// ---- wave-per-row top-8 + softmax + V gather ------------------------------
__global__ __launch_bounds__(256)
void topk_k(const float* __restrict__ sc, const float* __restrict__ vb,
            float* __restrict__ rpre, int r0)
{
  const float NEG = -__builtin_inff();
  int wave = threadIdx.x >> 6, lane = threadIdx.x & 63;
  int rowl = blockIdx.x * 4 + wave;
  int rowg = r0 + rowl;
  int b = rowg >> 9;
  const float* srow = sc + (size_t)rowl * N_;
  float v[8];
  #pragma unroll
  for (int j = 0; j < 8; ++j) v[j] = srow[lane + j * 64];
  float tv[8]; int ti[8];
  #pragma unroll
  for (int it = 0; it < 8; ++it) {
    float bv = v[0]; int bi = lane;
    #pragma unroll
    for (int j = 1; j < 8; ++j)
      if (v[j] > bv) { bv = v[j]; bi = lane + j * 64; }
    #pragma unroll
    for (int off = 1; off < 64; off <<= 1) {
      float ov = __shfl_xor(bv, off, 64);
      int   oi = __shfl_xor(bi, off, 64);
      if (ov > bv || (ov == bv && oi < bi)) { bv = ov; bi = oi; }
    }
    tv[it] = bv; ti[it] = bi;
    if ((bi & 63) == lane) v[bi >> 6] = NEG;
  }
  float mx = tv[0];
  float wsum = 0.f, wj[8];
  #pragma unroll
  for (int j = 0; j < 8; ++j) { wj[j] = expf(tv[j] - mx); wsum += wj[j]; }
  float inv = 1.0f / wsum;
  int d0 = lane * 4;
  float4 acc = {0.f, 0.f, 0.f, 0.f};
  #pragma unroll
  for (int j = 0; j < 8; ++j) {
    float wgt = wj[j] * inv;
    const float4 vv = *(const float4*)&vb[((size_t)(b * N_ + ti[j])) * 256 + d0];
    acc.x += wgt * vv.x; acc.y += wgt * vv.y; acc.z += wgt * vv.z; acc.w += wgt * vv.w;
  }
  *(float4*)&rpre[(size_t)rowg * 256 + d0] = acc;
}

// ---- KL scalar ------------------------------------------------------------
__global__ void kl_k(const float* __restrict__ hp, float* __restrict__ out)
{
  if (threadIdx.x == 0 && blockIdx.x == 0) {
    float hm = 0.f;
    for (int b = 0; b < 32; ++b) hm += hp[b];
    hm *= (1.0f / 32.0f);
    const float l1e8 = logf(1e-8f);
    float kl = 0.f;
    kl += 0.2f    * (logf(0.2f)    - l1e8);
    kl += 0.16f   * (logf(0.16f)   - l1e8);
    kl += 0.128f  * (logf(0.128f)  - logf(hm + 1e-8f));
    kl += 0.1024f * (logf(0.1024f) - logf(1.0f + 1e-8f));
    out[0] = kl * 0.25f;
  }
}

// ---------------------------------------------------------------------------
extern "C" void kernel_launch(void* const* d_in, const int* in_sizes, int n_in,
                              void* d_out, int out_size, void* d_ws, size_t ws_size,
                              hipStream_t stream)
{
  const int*   x       = (const int*)  d_in[0];
  const float* emb     = (const float*)d_in[1];
  const float* pos     = (const float*)d_in[2];
  const float* gru_wih = (const float*)d_in[3];
  const float* gru_whh = (const float*)d_in[4];
  const float* gru_bih = (const float*)d_in[5];
  const float* gru_bhh = (const float*)d_in[6];
  const float* pp_ln_g = (const float*)d_in[7];
  const float* pp_ln_b = (const float*)d_in[8];
  const float* sum_w   = (const float*)d_in[9];
  const float* sum_b   = (const float*)d_in[10];
  const float* msg_w1  = (const float*)d_in[11];
  const float* msg_b1  = (const float*)d_in[12];
  const float* msg_w2  = (const float*)d_in[13];
  const float* msg_b2  = (const float*)d_in[14];
  const float* upd_w1  = (const float*)d_in[15];
  const float* upd_b1  = (const float*)d_in[16];
  const float* upd_w2  = (const float*)d_in[17];
  const float* upd_b2  = (const float*)d_in[18];
  const float* halt_w  = (const float*)d_in[19];
  const float* halt_b  = (const float*)d_in[20];
  const float* mp_ln_g = (const float*)d_in[21];
  const float* mp_ln_b = (const float*)d_in[22];
  const float* q_w     = (const float*)d_in[23];
  const float* q_b     = (const float*)d_in[24];
  const float* k_w     = (const float*)d_in[25];
  const float* k_b     = (const float*)d_in[26];
  const float* v_w     = (const float*)d_in[27];
  const float* v_b     = (const float*)d_in[28];
  const float* o_w     = (const float*)d_in[29];
  const float* o_b     = (const float*)d_in[30];
  const float* br_w    = (const float*)d_in[31];
  const float* br_b    = (const float*)d_in[32];
  const float* f_ln_g  = (const float*)d_in[33];
  const float* f_ln_b  = (const float*)d_in[34];
  const float* head_w  = (const float*)d_in[35];

  // ---- workspace layout (~104 MB) ----
  constexpr size_t SZ_Q = (size_t)BN_ * 256;   // 4,194,304 floats
  float* ws     = (float*)d_ws;
  float* R_h    = ws;                  // h; later sc (16x512x512 = SZ_Q)
  float* R_outp = R_h    + SZ_Q;
  float* R_b1   = R_outp + SZ_Q;       // gh spans b1..b3; hsn spans b1..b2
  float* R_b2   = R_b1   + SZ_Q;
  float* R_b3   = R_b2   + SZ_Q;
  float* R_rp   = R_b3   + SZ_Q;       // rpre
  unsigned short* wb = (unsigned short*)(R_rp + SZ_Q);
  unsigned short* sumT  = wb;                  // [256][256] each
  unsigned short* W1cT  = sumT  + 65536;       // [512][256]
  unsigned short* m2T   = W1cT  + 131072;
  unsigned short* u1aT  = m2T   + 65536;
  unsigned short* u1bT  = u1aT  + 65536;
  unsigned short* u2T   = u1bT  + 65536;
  unsigned short* qT    = u2T   + 65536;
  unsigned short* kTt   = qT    + 65536;
  unsigned short* vT    = kTt   + 65536;
  unsigned short* oT    = vT    + 65536;
  unsigned short* brT   = oT    + 65536;
  unsigned short* headT = brT   + 65536;
  unsigned short* whhT  = headT + 65536;       // [768][256] straight
  float* R_embW = (float*)(whhT + 196608);     // 320 x 768
  float* R_bU   = R_embW + 320 * 768;          // 256
  float* R_bH   = R_bU + 256;                  // 512
  float* R_part = R_bH + 512;                  // 512
  float* R_hp   = R_part + 512;                // 32

  float* local  = (float*)d_out;
  float* logits = (float*)d_out;
  dim3 blk(256);

  // ---- prep: bf16 weights ----
  PrepJobs pj;
  const float* srcs[14] = {sum_w, msg_w1, msg_w1 + 65536, msg_w2,
                           upd_w1, upd_w1 + 65536, upd_w2,
                           q_w, k_w, v_w, o_w, br_w, head_w, gru_whh};
  unsigned short* dsts[14] = {sumT, W1cT, W1cT + 65536, m2T,
                              u1aT, u1bT, u2T, qT, kTt, vT, oT, brT, headT, whhT};
  int rows[14] = {256,256,256,256,256,256,256,256,256,256,256,256,256,768};
  int strt[14] = {0,0,0,0,0,0,0,0,0,0,0,0,0,1};
  for (int i = 0; i < 14; ++i) {
    pj.src[i]=srcs[i]; pj.dst[i]=dsts[i]; pj.rows[i]=rows[i]; pj.strt[i]=strt[i];
  }
  prep_w_k<<<dim3(64, 14), blk, 0, stream>>>(pj);
  biasprep_k<<<dim3(1), blk, 0, stream>>>(upd_b1, msg_b2, upd_w1, msg_b1, R_bU, R_bH);

  // embW = [emb; pos] @ wih^T (no bias; bih added in gru_pw)
  gemm_mfma<6, 1, 0><<<dim3(12, 5), blk, 0, stream>>>(
      nullptr, gru_wih, nullptr, R_embW, 320, 768, 256, 256,
      nullptr, emb, pos, 0, 0, 0);

  // ---- patch GRU: 4 steps, full-width ----
  hipMemsetAsync(R_h, 0, SZ_Q * sizeof(float), stream);
  float* ghbuf = R_b1;
  for (int t = 0; t < 4; ++t) {
    gemm_mfma<0, 0, 0><<<dim3(12, 256), blk, 0, stream>>>(
        R_h, whhT, gru_bhh, ghbuf, BN_, 768, 256, 256,
        nullptr, nullptr, nullptr, 0, 0, 0);
    gru_pw_k<<<dim3(BN_), blk, 0, stream>>>(
        ghbuf, R_embW, x, gru_bih, R_h, local, t);
  }
  ln_k<<<dim3(M1_ / 4), blk, 0, stream>>>(local, nullptr, 0, pp_ln_g, pp_ln_b, M1_);

  // summaries -> h
  gemm_mfma<4, 0, 0><<<dim3(4, 256), blk, 0, stream>>>(
      local, sumT, sum_b, R_h, BN_, 256, 256, 256,
      nullptr, nullptr, nullptr, 0, 0, 0);

  // ---- message-passing rounds ----
  for (int step = 0; step < 4; ++step) {
    // hsn = h @ [W1a|W1b]^T + [b1|0]   (BN x 512, in b1..b2)
    gemm_mfma<0, 0, 0><<<dim3(8, 256), blk, 0, stream>>>(
        R_h, W1cT, R_bH, R_b1, BN_, 512, 256, 256,
        nullptr, nullptr, nullptr, 0, 0, 0);
    // S = sum_kk gelu(hs + shift(hn))  -> b3
    smsg_k<<<dim3(BN_ / 4), blk, 0, stream>>>(R_b1, R_b3);
    // T = S @ W2^T -> b1
    gemm_mfma<0, 0, 0><<<dim3(4, 256), blk, 0, stream>>>(
        R_b3, m2T, nullptr, R_b1, BN_, 256, 256, 256,
        nullptr, nullptr, nullptr, 0, 0, 0);
    // P = rowscale(T @ U1b^T) -> b2
    gemm_mfma<0, 0, 3><<<dim3(4, 256), blk, 0, stream>>>(
        R_b1, u1bT, nullptr, R_b2, BN_, 256, 256, 256,
        nullptr, nullptr, nullptr, 0, 0, 0);
    // U = gelu(h @ U1a^T + P + biasU) -> b3
    gemm_mfma<0, 0, 4><<<dim3(4, 256), blk, 0, stream>>>(
        R_h, u1aT, R_bU, R_b3, BN_, 256, 256, 256,
        R_b2, nullptr, nullptr, 0, 0, 0);
    // upd = U @ U2^T + b2u -> b1
    gemm_mfma<0, 0, 0><<<dim3(4, 256), blk, 0, stream>>>(
        R_b3, u2T, upd_b2, R_b1, BN_, 256, 256, 256,
        nullptr, nullptr, nullptr, 0, 0, 0);
    // h = LN(h + upd)
    ln_k<<<dim3(BN_ / 4), blk, 0, stream>>>(R_h, R_b1, 0, mp_ln_g, mp_ln_b, BN_);
    if (step == 2) {
      halt1_k<<<dim3(32, 16), blk, 0, stream>>>(R_h, halt_w, R_part);
      halt2_k<<<dim3(1), dim3(64), 0, stream>>>(R_part, halt_b, R_hp);
      out2_k<<<dim3(BN_), blk, 0, stream>>>(R_h, R_hp, R_outp);
    } else if (step == 3) {
      out3_k<<<dim3(BN_), blk, 0, stream>>>(R_h, R_hp, R_outp);
    }
  }

  // ---- sparse retrieval attention ----
  float* qb = R_b1;
  float* kb = R_b2;
  float* vb = R_b3;
  float* sc = R_h;     // h dead
  gemm_mfma<0, 0, 0><<<dim3(4, 256), blk, 0, stream>>>(
      R_outp, qT, q_b, qb, BN_, 256, 256, 256, nullptr, nullptr, nullptr, 0, 0, 0);
  gemm_mfma<0, 0, 0><<<dim3(4, 256), blk, 0, stream>>>(
      R_outp, kTt, k_b, kb, BN_, 256, 256, 256, nullptr, nullptr, nullptr, 0, 0, 0);
  gemm_mfma<0, 0, 0><<<dim3(4, 256), blk, 0, stream>>>(
      R_outp, vT, v_b, vb, BN_, 256, 256, 256, nullptr, nullptr, nullptr, 0, 0, 0);
  for (int half = 0; half < 2; ++half) {
    size_t bo = (size_t)half * 16 * N_ * 256;
    gemm_mfma<0, 1, 2><<<dim3(8, 8, 16), blk, 0, stream>>>(
        qb + bo, kb + bo, nullptr, sc, N_, N_, 256, 256,
        nullptr, nullptr, nullptr,
        (size_t)N_ * 256, (size_t)N_ * 256, (size_t)N_ * N_);
    topk_k<<<dim3(BN_ / 8), blk, 0, stream>>>(sc, vb, R_rp, half * 16 * N_);
  }
  float* retr  = R_b2;   // kb dead
  float* broad = R_b1;   // qb dead
  gemm_mfma<0, 0, 0><<<dim3(4, 256), blk, 0, stream>>>(
      R_rp, oT, o_b, retr, BN_, 256, 256, 256, nullptr, nullptr, nullptr, 0, 0, 0);
  gemm_mfma<5, 0, 0><<<dim3(4, 256), blk, 0, stream>>>(
      R_outp, brT, br_b, broad, BN_, 256, 256, 256, retr, nullptr, nullptr, 0, 0, 0);

  // final LN + bf16 convert -> Abuf (b2..b3), then head GEMM -> d_out
  unsigned short* Abuf = (unsigned short*)R_b2;   // retr/vb dead
  ln_cvt_k<<<dim3(M1_ / 4), blk, 0, stream>>>(local, broad, f_ln_g, f_ln_b, Abuf);
  gemm_mfma<7, 0, 0><<<dim3(4, 1024), blk, 0, stream>>>(
      (const float*)Abuf, headT, nullptr, logits, M1_, 256, 256, 256,
      nullptr, nullptr, nullptr, 0, 0, 0);

  kl_k<<<dim3(1), dim3(64), 0, stream>>>(R_hp, logits + (size_t)M1_ * 256);
}

// Round 6
// 721.664 us; speedup vs baseline: 6.4031x; 1.3104x over previous
//
#include <hip/hip_runtime.h>
#include <cmath>

// ---------------------------------------------------------------------------
// SutraV04 round 5: round-4 design with the workspace units bug fixed
// (wb must be R_loc + 4*SZ_Q SHORTS = 2*SZ_Q floats).
//  - causal tri-tile XCD-swizzled scores
//  - msg-MLP algebra (Wc = msg_w2@U1b precomputed, P+U fused concat GEMM)
//  - bf16 activations (gh, hsn, U, local, q/k/v, rpre)
// ---------------------------------------------------------------------------

constexpr int N_   = 512;
constexpr int B_   = 32;
constexpr int BN_  = B_ * N_;   // 16384
constexpr int M1_  = BN_ * 4;   // 65536

typedef short bf16x8 __attribute__((ext_vector_type(8)));
typedef float f32x4  __attribute__((ext_vector_type(4)));

__device__ __forceinline__ float gelu_f(float x) {
  return 0.5f * x * (1.0f + erff(x * 0.70710678118654752440f));
}
__device__ __forceinline__ float sigm_f(float x) {
  return 1.0f / (1.0f + expf(-x));
}
__device__ __forceinline__ unsigned short f2bf(float f) {
  union { float f; unsigned int u; } c; c.f = f;
  unsigned int u = c.u;
  u += 0x7FFFu + ((u >> 16) & 1u);
  return (unsigned short)(u >> 16);
}
__device__ __forceinline__ float bf2f(unsigned short u) {
  union { unsigned int u; float f; } c; c.u = ((unsigned int)u) << 16;
  return c.f;
}
__device__ __forceinline__ int phys(int g, int r) {
  return ((g << 6) | (r ^ g)) << 3;   // shorts
}

// ---- A gathers: 8 values at [m][k..k+8) -----------------------------------
// 0 f32 [m][K]; 3 concat(h f32 | P2=S' f32); 5 A+P2 f32; 6 emb/pos rows;
// 7 bf16 [m][K]; 8 transposed upd_w1 gather (Wc prep); 9 bf16 patch-mean
template<int MODE>
__device__ __forceinline__ void loadA8(float v[8], const float* __restrict__ A,
    const float* __restrict__ P2, const float* __restrict__ emb,
    const float* __restrict__ pos, int m, int k, int K)
{
  if constexpr (MODE == 0) {
    const float4* p = (const float4*)(A + (size_t)m * K + k);
    float4 a = p[0], b = p[1];
    v[0]=a.x; v[1]=a.y; v[2]=a.z; v[3]=a.w; v[4]=b.x; v[5]=b.y; v[6]=b.z; v[7]=b.w;
  } else if constexpr (MODE == 3) {
    const float* src = (k < 256) ? (A + (size_t)m * 256 + k)
                                 : (P2 + (size_t)m * 256 + (k - 256));
    const float4* p = (const float4*)src;
    float4 a = p[0], b = p[1];
    v[0]=a.x; v[1]=a.y; v[2]=a.z; v[3]=a.w; v[4]=b.x; v[5]=b.y; v[6]=b.z; v[7]=b.w;
  } else if constexpr (MODE == 5) {
    const float4* p = (const float4*)(A  + (size_t)m * 256 + k);
    const float4* q = (const float4*)(P2 + (size_t)m * 256 + k);
    float4 a=p[0], b=p[1], c=q[0], d=q[1];
    v[0]=a.x+c.x; v[1]=a.y+c.y; v[2]=a.z+c.z; v[3]=a.w+c.w;
    v[4]=b.x+d.x; v[5]=b.y+d.y; v[6]=b.z+d.z; v[7]=b.w+d.w;
  } else if constexpr (MODE == 6) {
    const float* src = nullptr;
    if (m < 256) src = emb + (size_t)m * 256 + k;
    else if (m < 260) src = pos + (size_t)(m - 256) * 256 + k;
    if (src) {
      const float4* p = (const float4*)src;
      float4 a = p[0], b = p[1];
      v[0]=a.x; v[1]=a.y; v[2]=a.z; v[3]=a.w; v[4]=b.x; v[5]=b.y; v[6]=b.z; v[7]=b.w;
    } else {
      #pragma unroll
      for (int j = 0; j < 8; ++j) v[j] = 0.f;
    }
  } else if constexpr (MODE == 8) {
    #pragma unroll
    for (int j = 0; j < 8; ++j)
      v[j] = P2[(size_t)(256 + k + j) * 256 + m];
  } else { // 9
    const unsigned short* Ab = (const unsigned short*)A;
    const unsigned short* base = Ab + (size_t)m * 1024 + k;
    bf16x8 r0 = *(const bf16x8*)(base);
    bf16x8 r1 = *(const bf16x8*)(base + 256);
    bf16x8 r2 = *(const bf16x8*)(base + 512);
    bf16x8 r3 = *(const bf16x8*)(base + 768);
    #pragma unroll
    for (int j = 0; j < 8; ++j)
      v[j] = 0.25f * (bf2f((unsigned short)r0[j]) + bf2f((unsigned short)r1[j]) +
                      bf2f((unsigned short)r2[j]) + bf2f((unsigned short)r3[j]));
  }
}

// ---- MFMA GEMM: C[M,Nn](ldC) = epi(gatherA[M,K] @ Bt[Nn,K]^T + bias) ------
// BSRC: 0 bf16 Bt[n][bstride]; 1 fp32. EPI: 0 none, 1 gelu. COUT: 0 f32, 1 bf16.
template<int MODE, int BSRC, int EPI, int COUT>
__global__ __launch_bounds__(256)
void gemm_mfma(const float* __restrict__ A, const void* __restrict__ Bsrc,
               const float* __restrict__ bias, void* __restrict__ C,
               int M, int Nn, int K, int bstride, int ldC,
               const float* __restrict__ P2,
               const float* __restrict__ emb, const float* __restrict__ pos)
{
  __shared__ short As[4 * 64 * 8];
  __shared__ short Bs[4 * 64 * 8];
  const int tid  = threadIdx.x;
  const int m0   = blockIdx.y * 64, n0 = blockIdx.x * 64;
  const int srow = tid >> 2, sg = tid & 3;
  const int lane = tid & 63, w = tid >> 6;
  const int wr   = w >> 1,  wc = w & 1;
  const int fr   = lane & 15, fg = lane >> 4;

  f32x4 acc[2][2] = {};

  for (int k0 = 0; k0 < K; k0 += 32) {
    if constexpr (MODE == 7) {
      const unsigned short* Ab = (const unsigned short*)A;
      *(bf16x8*)&As[phys(sg, srow)] =
          *(const bf16x8*)&Ab[(size_t)(m0 + srow) * K + k0 + sg * 8];
    } else {
      float v[8];
      loadA8<MODE>(v, A, P2, emb, pos, m0 + srow, k0 + sg * 8, K);
      bf16x8 tv;
      #pragma unroll
      for (int j = 0; j < 8; ++j) tv[j] = (short)f2bf(v[j]);
      *(bf16x8*)&As[phys(sg, srow)] = tv;
    }
    if constexpr (BSRC == 0) {
      const unsigned short* Bt = (const unsigned short*)Bsrc;
      *(bf16x8*)&Bs[phys(sg, srow)] =
          *(const bf16x8*)&Bt[(size_t)(n0 + srow) * bstride + k0 + sg * 8];
    } else {
      const float* Bf = (const float*)Bsrc;
      const float4* p = (const float4*)(Bf + (size_t)(n0 + srow) * bstride + k0 + sg * 8);
      float4 a = p[0], b = p[1];
      bf16x8 tv;
      tv[0]=(short)f2bf(a.x); tv[1]=(short)f2bf(a.y); tv[2]=(short)f2bf(a.z); tv[3]=(short)f2bf(a.w);
      tv[4]=(short)f2bf(b.x); tv[5]=(short)f2bf(b.y); tv[6]=(short)f2bf(b.z); tv[7]=(short)f2bf(b.w);
      *(bf16x8*)&Bs[phys(sg, srow)] = tv;
    }
    __syncthreads();

    bf16x8 a0 = *(const bf16x8*)&As[phys(fg, wr * 32 + fr)];
    bf16x8 a1 = *(const bf16x8*)&As[phys(fg, wr * 32 + 16 + fr)];
    bf16x8 b0 = *(const bf16x8*)&Bs[phys(fg, wc * 32 + fr)];
    bf16x8 b1 = *(const bf16x8*)&Bs[phys(fg, wc * 32 + 16 + fr)];
    acc[0][0] = __builtin_amdgcn_mfma_f32_16x16x32_bf16(a0, b0, acc[0][0], 0, 0, 0);
    acc[0][1] = __builtin_amdgcn_mfma_f32_16x16x32_bf16(a0, b1, acc[0][1], 0, 0, 0);
    acc[1][0] = __builtin_amdgcn_mfma_f32_16x16x32_bf16(a1, b0, acc[1][0], 0, 0, 0);
    acc[1][1] = __builtin_amdgcn_mfma_f32_16x16x32_bf16(a1, b1, acc[1][1], 0, 0, 0);
    __syncthreads();
  }

  #pragma unroll
  for (int i = 0; i < 2; ++i) {
    #pragma unroll
    for (int j = 0; j < 2; ++j) {
      int row0 = m0 + wr * 32 + i * 16 + fg * 4;
      int col  = n0 + wc * 32 + j * 16 + fr;
      float bcol = bias ? bias[col] : 0.0f;
      #pragma unroll
      for (int r = 0; r < 4; ++r) {
        float vv = acc[i][j][r] + bcol;
        if constexpr (EPI == 1) vv = gelu_f(vv);
        int row = row0 + r;
        if constexpr (COUT == 0)
          ((float*)C)[(size_t)row * ldC + col] = vv;
        else
          ((unsigned short*)C)[(size_t)row * ldC + col] = f2bf(vv);
      }
    }
  }
}

// ---- causal tri-tile scores, XCD-swizzled, bf16 in / f32 out --------------
__global__ __launch_bounds__(256)
void scores_tri(const unsigned short* __restrict__ qb,
                const unsigned short* __restrict__ kb,
                float* __restrict__ sc)
{
  int flat = blockIdx.x;
  int xcd = flat & 7, s = flat >> 3;
  int bhi = s / 36, tile = s - bhi * 36;
  int b = bhi * 8 + xcd;
  int ti = 0;
  while ((ti + 1) * (ti + 2) / 2 <= tile) ++ti;
  int tj = tile - ti * (ti + 1) / 2;
  const int m0 = ti * 64, n0 = tj * 64;
  const unsigned short* Aq = qb + (size_t)b * N_ * 256;
  const unsigned short* Bk = kb + (size_t)b * N_ * 256;

  __shared__ short As[4 * 64 * 8];
  __shared__ short Bs[4 * 64 * 8];
  const int tid  = threadIdx.x;
  const int srow = tid >> 2, sg = tid & 3;
  const int lane = tid & 63, w = tid >> 6;
  const int wr   = w >> 1,  wc = w & 1;
  const int fr   = lane & 15, fg = lane >> 4;

  f32x4 acc[2][2] = {};
  for (int k0 = 0; k0 < 256; k0 += 32) {
    *(bf16x8*)&As[phys(sg, srow)] =
        *(const bf16x8*)&Aq[(size_t)(m0 + srow) * 256 + k0 + sg * 8];
    *(bf16x8*)&Bs[phys(sg, srow)] =
        *(const bf16x8*)&Bk[(size_t)(n0 + srow) * 256 + k0 + sg * 8];
    __syncthreads();
    bf16x8 a0 = *(const bf16x8*)&As[phys(fg, wr * 32 + fr)];
    bf16x8 a1 = *(const bf16x8*)&As[phys(fg, wr * 32 + 16 + fr)];
    bf16x8 b0 = *(const bf16x8*)&Bs[phys(fg, wc * 32 + fr)];
    bf16x8 b1 = *(const bf16x8*)&Bs[phys(fg, wc * 32 + 16 + fr)];
    acc[0][0] = __builtin_amdgcn_mfma_f32_16x16x32_bf16(a0, b0, acc[0][0], 0, 0, 0);
    acc[0][1] = __builtin_amdgcn_mfma_f32_16x16x32_bf16(a0, b1, acc[0][1], 0, 0, 0);
    acc[1][0] = __builtin_amdgcn_mfma_f32_16x16x32_bf16(a1, b0, acc[1][0], 0, 0, 0);
    acc[1][1] = __builtin_amdgcn_mfma_f32_16x16x32_bf16(a1, b1, acc[1][1], 0, 0, 0);
    __syncthreads();
  }
  float* scb = sc + (size_t)b * N_ * N_;
  #pragma unroll
  for (int i = 0; i < 2; ++i) {
    #pragma unroll
    for (int j = 0; j < 2; ++j) {
      int row0 = m0 + wr * 32 + i * 16 + fg * 4;
      int col  = n0 + wc * 32 + j * 16 + fr;
      #pragma unroll
      for (int r = 0; r < 4; ++r) {
        int row = row0 + r;
        float vv = acc[i][j][r] * 0.0625f;
        if (col > row) vv = -__builtin_inff();
        scb[(size_t)row * N_ + col] = vv;
      }
    }
  }
}

// ---- weight prep: bf16 cast/transpose with dest stride --------------------
struct PrepJobs {
  const float* src[12];
  unsigned short* dst[12];
  int rows[12];
  int dstride[12];
  int strt[12];
};
__global__ __launch_bounds__(256)
void prep_w_k(PrepJobs pj)
{
  int jid = blockIdx.y;
  const float* src = pj.src[jid];
  unsigned short* dst = pj.dst[jid];
  int ds = pj.dstride[jid];
  int total = pj.rows[jid] << 8;
  if (pj.strt[jid]) {
    for (int i = blockIdx.x * 256 + threadIdx.x; i < total; i += gridDim.x * 256) {
      int k = i & 255, n = i >> 8;
      dst[(size_t)n * ds + k] = f2bf(src[i]);
    }
  } else {
    for (int i = blockIdx.x * 256 + threadIdx.x; i < total; i += gridDim.x * 256) {
      int k = i & 255, n = i >> 8;
      dst[(size_t)n * ds + k] = f2bf(src[(size_t)k * 256 + n]);
    }
  }
}

// ---- bias prep ------------------------------------------------------------
__global__ __launch_bounds__(256)
void biasprep_k(const float* __restrict__ upd_b1, const float* __restrict__ msg_b2,
                const float* __restrict__ upd_w1, const float* __restrict__ msg_b1,
                float* __restrict__ biasU, float* __restrict__ biasHsn)
{
  int c = threadIdx.x;
  float s = upd_b1[c];
  for (int k = 0; k < 256; ++k)
    s += msg_b2[k] * upd_w1[(size_t)(256 + k) * 256 + c];
  biasU[c] = s;
  biasHsn[c] = msg_b1[c];
  biasHsn[256 + c] = 0.f;
}

// ---- GRU pointwise: gh bf16 (or bhh broadcast at t=0), local bf16 ---------
template<int FIRST>
__global__ __launch_bounds__(256)
void gru_pw_k(const unsigned short* __restrict__ gh, const float* __restrict__ bhh,
              const float* __restrict__ embW, const int* __restrict__ x,
              const float* __restrict__ bih,
              float* __restrict__ h, unsigned short* __restrict__ local, int t)
{
  int i   = blockIdx.x * 256 + threadIdx.x;
  int row = i >> 8, d = i & 255;
  int tok = x[row * 4 + t];
  const float* er = embW + (size_t)tok * 768;
  const float* pr = embW + (size_t)(256 + t) * 768;
  float ir  = er[d]       + pr[d]       + bih[d];
  float iz  = er[256 + d] + pr[256 + d] + bih[256 + d];
  float inn = er[512 + d] + pr[512 + d] + bih[512 + d];
  float hr, hz, hn;
  if constexpr (FIRST) {
    hr = bhh[d]; hz = bhh[256 + d]; hn = bhh[512 + d];
  } else {
    const unsigned short* gr = gh + (size_t)row * 768;
    hr = bf2f(gr[d]); hz = bf2f(gr[256 + d]); hn = bf2f(gr[512 + d]);
  }
  float r  = sigm_f(ir + hr);
  float zg = sigm_f(iz + hz);
  float nn = tanhf(inn + r * hn);
  float hnew;
  if constexpr (FIRST) hnew = (1.0f - zg) * nn;
  else                 hnew = (1.0f - zg) * nn + zg * h[i];
  h[i] = hnew;
  local[((size_t)row * 4 + t) * 256 + d] = f2bf(hnew);
}

// ---- S' = rowscale( sum_kk gelu(hs + shift(hn)) ), hsn bf16 -> f32 --------
__global__ __launch_bounds__(256)
void smsg_k(const unsigned short* __restrict__ hsn, float* __restrict__ S)
{
  int i = blockIdx.x * 256 + threadIdx.x;   // BN*64
  int m = i >> 6, d4 = (i & 63) << 2;
  int n = m & (N_ - 1);
  ushort4 hsu = *(const ushort4*)&hsn[(size_t)m * 512 + d4];
  float hs0 = bf2f(hsu.x), hs1 = bf2f(hsu.y), hs2 = bf2f(hsu.z), hs3 = bf2f(hsu.w);
  float a0 = 0.f, a1 = 0.f, a2 = 0.f, a3 = 0.f;
  #pragma unroll
  for (int kk = 0; kk < 5; ++kk) {
    int idx = n + kk - 4;
    if (idx >= 0) {
      ushort4 hv = *(const ushort4*)&hsn[(size_t)(m + kk - 4) * 512 + 256 + d4];
      a0 += gelu_f(hs0 + bf2f(hv.x));
      a1 += gelu_f(hs1 + bf2f(hv.y));
      a2 += gelu_f(hs2 + bf2f(hv.z));
      a3 += gelu_f(hs3 + bf2f(hv.w));
    }
  }
  float sc1 = 1.0f / (float)((n < 4 ? n : 4) + 1);
  float4 o = {a0 * sc1, a1 * sc1, a2 * sc1, a3 * sc1};
  *(float4*)&S[(size_t)m * 256 + d4] = o;
}

// ---- LayerNorm f32 in place; OUTM=3: outp += (1-hp[b]) * y ----------------
template<int OUTM>
__global__ __launch_bounds__(256)
void ln_k(float* __restrict__ X, const float* __restrict__ Add,
          const float* __restrict__ g, const float* __restrict__ bb,
          const float* __restrict__ hp, float* __restrict__ outp)
{
  int wave = threadIdx.x >> 6, lane = threadIdx.x & 63;
  int row  = blockIdx.x * 4 + wave;
  float* xr = X + (size_t)row * 256;
  float x[4];
  #pragma unroll
  for (int j = 0; j < 4; ++j) x[j] = xr[lane * 4 + j];
  if (Add) {
    const float* ar = Add + (size_t)row * 256;
    #pragma unroll
    for (int j = 0; j < 4; ++j) x[j] += ar[lane * 4 + j];
  }
  float s = x[0] + x[1] + x[2] + x[3];
  #pragma unroll
  for (int off = 1; off < 64; off <<= 1) s += __shfl_xor(s, off, 64);
  float mean = s * (1.0f / 256.0f);
  float ss = 0.f;
  #pragma unroll
  for (int j = 0; j < 4; ++j) { float d = x[j] - mean; ss += d * d; }
  #pragma unroll
  for (int off = 1; off < 64; off <<= 1) ss += __shfl_xor(ss, off, 64);
  float inv = rsqrtf(ss * (1.0f / 256.0f) + 1e-5f);
  float rem = 0.f;
  if constexpr (OUTM == 3) rem = 1.0f - hp[row >> 9];
  #pragma unroll
  for (int j = 0; j < 4; ++j) {
    float y = (x[j] - mean) * inv * g[lane * 4 + j] + bb[lane * 4 + j];
    xr[lane * 4 + j] = y;
    if constexpr (OUTM == 3) outp[(size_t)row * 256 + lane * 4 + j] += rem * y;
  }
}

// ---- LayerNorm bf16 in place (pp_ln on local) -----------------------------
__global__ __launch_bounds__(256)
void ln_bf16_k(unsigned short* __restrict__ X, const float* __restrict__ g,
               const float* __restrict__ bb)
{
  int wave = threadIdx.x >> 6, lane = threadIdx.x & 63;
  int row  = blockIdx.x * 4 + wave;
  unsigned short* xr = X + (size_t)row * 256;
  ushort4 u = *(const ushort4*)&xr[lane * 4];
  float x[4] = {bf2f(u.x), bf2f(u.y), bf2f(u.z), bf2f(u.w)};
  float s = x[0] + x[1] + x[2] + x[3];
  #pragma unroll
  for (int off = 1; off < 64; off <<= 1) s += __shfl_xor(s, off, 64);
  float mean = s * (1.0f / 256.0f);
  float ss = 0.f;
  #pragma unroll
  for (int j = 0; j < 4; ++j) { float d = x[j] - mean; ss += d * d; }
  #pragma unroll
  for (int off = 1; off < 64; off <<= 1) ss += __shfl_xor(ss, off, 64);
  float inv = rsqrtf(ss * (1.0f / 256.0f) + 1e-5f);
  ushort4 o;
  o.x = f2bf((x[0] - mean) * inv * g[lane*4+0] + bb[lane*4+0]);
  o.y = f2bf((x[1] - mean) * inv * g[lane*4+1] + bb[lane*4+1]);
  o.z = f2bf((x[2] - mean) * inv * g[lane*4+2] + bb[lane*4+2]);
  o.w = f2bf((x[3] - mean) * inv * g[lane*4+3] + bb[lane*4+3]);
  *(ushort4*)&xr[lane * 4] = o;
}

// ---- final LN: local bf16 + broad f32 -> Abuf bf16 ------------------------
__global__ __launch_bounds__(256)
void ln_cvt_k(const unsigned short* __restrict__ X, const float* __restrict__ Add,
              const float* __restrict__ g, const float* __restrict__ bb,
              unsigned short* __restrict__ Out)
{
  int wave = threadIdx.x >> 6, lane = threadIdx.x & 63;
  int row  = blockIdx.x * 4 + wave;
  ushort4 u = *(const ushort4*)&X[(size_t)row * 256 + lane * 4];
  const float4 ar = *(const float4*)&Add[(size_t)(row >> 2) * 256 + lane * 4];
  float x[4] = {bf2f(u.x) + ar.x, bf2f(u.y) + ar.y, bf2f(u.z) + ar.z, bf2f(u.w) + ar.w};
  float s = x[0] + x[1] + x[2] + x[3];
  #pragma unroll
  for (int off = 1; off < 64; off <<= 1) s += __shfl_xor(s, off, 64);
  float mean = s * (1.0f / 256.0f);
  float ss = 0.f;
  #pragma unroll
  for (int j = 0; j < 4; ++j) { float d = x[j] - mean; ss += d * d; }
  #pragma unroll
  for (int off = 1; off < 64; off <<= 1) ss += __shfl_xor(ss, off, 64);
  float inv = rsqrtf(ss * (1.0f / 256.0f) + 1e-5f);
  ushort4 o;
  o.x = f2bf((x[0] - mean) * inv * g[lane*4+0] + bb[lane*4+0]);
  o.y = f2bf((x[1] - mean) * inv * g[lane*4+1] + bb[lane*4+1]);
  o.z = f2bf((x[2] - mean) * inv * g[lane*4+2] + bb[lane*4+2]);
  o.w = f2bf((x[3] - mean) * inv * g[lane*4+3] + bb[lane*4+3]);
  *(ushort4*)&Out[(size_t)row * 256 + lane * 4] = o;
}

// ---- halting: 2-stage reduction -------------------------------------------
__global__ __launch_bounds__(256)
void halt1_k(const float* __restrict__ h, const float* __restrict__ hw,
             float* __restrict__ part)
{
  int b = blockIdx.x, s = blockIdx.y, tid = threadIdx.x;
  const float* p = h + ((size_t)b * N_ + s * 32) * 256;
  float acc = 0.f;
  for (int i = tid; i < 32 * 256; i += 256) acc += p[i] * hw[i & 255];
  __shared__ float red[256];
  red[tid] = acc; __syncthreads();
  for (int off = 128; off > 0; off >>= 1) {
    if (tid < off) red[tid] += red[tid + off];
    __syncthreads();
  }
  if (tid == 0) part[b * 16 + s] = red[0];
}
__global__ __launch_bounds__(64)
void halt2_k(const float* __restrict__ part, const float* __restrict__ hb,
             float* __restrict__ hp)
{
  int b = threadIdx.x;
  if (b < 32) {
    float s = 0.f;
    for (int i = 0; i < 16; ++i) s += part[b * 16 + i];
    hp[b] = sigm_f(s * (1.0f / (float)N_) + hb[0]);
  }
}

__global__ __launch_bounds__(256)
void out2_k(const float* __restrict__ h, const float* __restrict__ hp,
            float* __restrict__ outp)
{
  int i = blockIdx.x * 256 + threadIdx.x;
  outp[i] = hp[i >> 17] * h[i];
}

// ---- wave-per-row top-8 + softmax + bf16 V gather -> bf16 rpre ------------
__global__ __launch_bounds__(256)
void topk_k(const float* __restrict__ sc, const unsigned short* __restrict__ vb,
            unsigned short* __restrict__ rpre)
{
  const float NEG = -__builtin_inff();
  int wave = threadIdx.x >> 6, lane = threadIdx.x & 63;
  int rowg = blockIdx.x * 4 + wave;
  int b = rowg >> 9, n = rowg & (N_ - 1);
  const float* srow = sc + (size_t)rowg * N_;
  float v[8];
  #pragma unroll
  for (int j = 0; j < 8; ++j) {
    int col = lane + j * 64;
    v[j] = (col <= n) ? srow[col] : NEG;
  }
  float tv[8]; int ti[8];
  #pragma unroll
  for (int it = 0; it < 8; ++it) {
    float bv = v[0]; int bi = lane;
    #pragma unroll
    for (int j = 1; j < 8; ++j)
      if (v[j] > bv) { bv = v[j]; bi = lane + j * 64; }
    #pragma unroll
    for (int off = 1; off < 64; off <<= 1) {
      float ov = __shfl_xor(bv, off, 64);
      int   oi = __shfl_xor(bi, off, 64);
      if (ov > bv || (ov == bv && oi < bi)) { bv = ov; bi = oi; }
    }
    tv[it] = bv; ti[it] = bi;
    if ((bi & 63) == lane) v[bi >> 6] = NEG;
  }
  float mx = tv[0];
  float wsum = 0.f, wj[8];
  #pragma unroll
  for (int j = 0; j < 8; ++j) { wj[j] = expf(tv[j] - mx); wsum += wj[j]; }
  float inv = 1.0f / wsum;
  int d0 = lane * 4;
  float a0 = 0.f, a1 = 0.f, a2 = 0.f, a3 = 0.f;
  #pragma unroll
  for (int j = 0; j < 8; ++j) {
    float wgt = wj[j] * inv;
    ushort4 vv = *(const ushort4*)&vb[((size_t)(b * N_ + ti[j])) * 256 + d0];
    a0 += wgt * bf2f(vv.x); a1 += wgt * bf2f(vv.y);
    a2 += wgt * bf2f(vv.z); a3 += wgt * bf2f(vv.w);
  }
  ushort4 o = {f2bf(a0), f2bf(a1), f2bf(a2), f2bf(a3)};
  *(ushort4*)&rpre[(size_t)rowg * 256 + d0] = o;
}

// ---- KL scalar ------------------------------------------------------------
__global__ void kl_k(const float* __restrict__ hp, float* __restrict__ out)
{
  if (threadIdx.x == 0 && blockIdx.x == 0) {
    float hm = 0.f;
    for (int b = 0; b < 32; ++b) hm += hp[b];
    hm *= (1.0f / 32.0f);
    const float l1e8 = logf(1e-8f);
    float kl = 0.f;
    kl += 0.2f    * (logf(0.2f)    - l1e8);
    kl += 0.16f   * (logf(0.16f)   - l1e8);
    kl += 0.128f  * (logf(0.128f)  - logf(hm + 1e-8f));
    kl += 0.1024f * (logf(0.1024f) - logf(1.0f + 1e-8f));
    out[0] = kl * 0.25f;
  }
}

// ---------------------------------------------------------------------------
extern "C" void kernel_launch(void* const* d_in, const int* in_sizes, int n_in,
                              void* d_out, int out_size, void* d_ws, size_t ws_size,
                              hipStream_t stream)
{
  const int*   x       = (const int*)  d_in[0];
  const float* emb     = (const float*)d_in[1];
  const float* pos     = (const float*)d_in[2];
  const float* gru_wih = (const float*)d_in[3];
  const float* gru_whh = (const float*)d_in[4];
  const float* gru_bih = (const float*)d_in[5];
  const float* gru_bhh = (const float*)d_in[6];
  const float* pp_ln_g = (const float*)d_in[7];
  const float* pp_ln_b = (const float*)d_in[8];
  const float* sum_w   = (const float*)d_in[9];
  const float* sum_b   = (const float*)d_in[10];
  const float* msg_w1  = (const float*)d_in[11];
  const float* msg_b1  = (const float*)d_in[12];
  const float* msg_w2  = (const float*)d_in[13];
  const float* msg_b2  = (const float*)d_in[14];
  const float* upd_w1  = (const float*)d_in[15];
  const float* upd_b1  = (const float*)d_in[16];
  const float* upd_w2  = (const float*)d_in[17];
  const float* upd_b2  = (const float*)d_in[18];
  const float* halt_w  = (const float*)d_in[19];
  const float* halt_b  = (const float*)d_in[20];
  const float* mp_ln_g = (const float*)d_in[21];
  const float* mp_ln_b = (const float*)d_in[22];
  const float* q_w     = (const float*)d_in[23];
  const float* q_b     = (const float*)d_in[24];
  const float* k_w     = (const float*)d_in[25];
  const float* k_b     = (const float*)d_in[26];
  const float* v_w     = (const float*)d_in[27];
  const float* v_b     = (const float*)d_in[28];
  const float* o_w     = (const float*)d_in[29];
  const float* o_b     = (const float*)d_in[30];
  const float* br_w    = (const float*)d_in[31];
  const float* br_b    = (const float*)d_in[32];
  const float* f_ln_g  = (const float*)d_in[33];
  const float* f_ln_b  = (const float*)d_in[34];
  const float* head_w  = (const float*)d_in[35];

  // ---- workspace (floats): 8*SZ_Q = 134 MB + ~3.3 MB weights ----
  constexpr size_t SZ_Q = (size_t)BN_ * 256;
  float* ws     = (float*)d_ws;
  float* R_h    = ws;                  // h; later broad
  float* R_outp = R_h    + SZ_Q;
  float* R_b1   = R_outp + SZ_Q;       // gh/hsn/upd; sc lo; Abuf lo
  float* R_b2   = R_b1   + SZ_Q;       // gh hi/U; sc hi; Abuf hi
  float* R_b3   = R_b2   + SZ_Q;       // S'; qb+kb; retr
  float* R_rp   = R_b3   + SZ_Q;       // vb + rpre (bf16)
  unsigned short* R_loc = (unsigned short*)(R_rp + SZ_Q);   // local bf16, M1_*256 shorts
  // FIX (round 5): R_loc spans 4*SZ_Q SHORTS (= 2*SZ_Q floats). Round 4 used
  // R_loc + 2*SZ_Q (shorts) here, placing the weight tables inside local's
  // upper half -> GRU local-writes clobbered embW/weights -> NaN.
  unsigned short* wb = R_loc + 4 * SZ_Q;
  unsigned short* sumT  = wb;                  // [256][256]
  unsigned short* W1cT  = sumT  + 65536;       // [512][256]
  unsigned short* u1cT  = W1cT  + 131072;      // [256][512] = [U1a | Wc]
  unsigned short* u2T   = u1cT  + 131072;
  unsigned short* qT    = u2T   + 65536;
  unsigned short* kTt   = qT    + 65536;
  unsigned short* vT    = kTt   + 65536;
  unsigned short* oT    = vT    + 65536;
  unsigned short* brT   = oT    + 65536;
  unsigned short* headT = brT   + 65536;
  unsigned short* whhT  = headT + 65536;       // [768][256]
  float* R_embW = (float*)(whhT + 196608);     // [320][768]
  float* R_bU   = R_embW + 320 * 768;
  float* R_bH   = R_bU + 256;
  float* R_part = R_bH + 512;
  float* R_hp   = R_part + 512;

  float* logits = (float*)d_out;
  dim3 blk(256);

  // ---- weight prep ----
  PrepJobs pj;
  const float* srcs[12] = {sum_w, msg_w1, msg_w1 + 65536, upd_w1, upd_w2,
                           q_w, k_w, v_w, o_w, br_w, head_w, gru_whh};
  unsigned short* dsts[12] = {sumT, W1cT, W1cT + 65536, u1cT, u2T,
                              qT, kTt, vT, oT, brT, headT, whhT};
  int rows[12] = {256,256,256,256,256,256,256,256,256,256,256,768};
  int dstd[12] = {256,256,256,512,256,256,256,256,256,256,256,256};
  int strt[12] = {0,0,0,0,0,0,0,0,0,0,0,1};
  for (int i = 0; i < 12; ++i) {
    pj.src[i]=srcs[i]; pj.dst[i]=dsts[i]; pj.rows[i]=rows[i];
    pj.dstride[i]=dstd[i]; pj.strt[i]=strt[i];
  }
  prep_w_k<<<dim3(64, 12), blk, 0, stream>>>(pj);
  biasprep_k<<<dim3(1), blk, 0, stream>>>(upd_b1, msg_b2, upd_w1, msg_b1, R_bU, R_bH);
  // Wc = msg_w2 @ U1b  ->  u1cT cols 256.. (bf16, ldC=512)
  gemm_mfma<8, 1, 0, 1><<<dim3(4, 4), blk, 0, stream>>>(
      nullptr, msg_w2, nullptr, u1cT + 256, 256, 256, 256, 256, 512,
      upd_w1, nullptr, nullptr);
  // embW = [emb; pos] @ wih^T
  gemm_mfma<6, 1, 0, 0><<<dim3(12, 5), blk, 0, stream>>>(
      nullptr, gru_wih, nullptr, R_embW, 320, 768, 256, 256, 768,
      nullptr, emb, pos);

  // ---- patch GRU ----
  unsigned short* ghB = (unsigned short*)R_b1;
  gru_pw_k<1><<<dim3(BN_), blk, 0, stream>>>(
      nullptr, gru_bhh, R_embW, x, gru_bih, R_h, R_loc, 0);
  for (int t = 1; t < 4; ++t) {
    gemm_mfma<0, 0, 0, 1><<<dim3(12, 256), blk, 0, stream>>>(
        R_h, whhT, gru_bhh, ghB, BN_, 768, 256, 256, 768,
        nullptr, nullptr, nullptr);
    gru_pw_k<0><<<dim3(BN_), blk, 0, stream>>>(
        ghB, gru_bhh, R_embW, x, gru_bih, R_h, R_loc, t);
  }
  ln_bf16_k<<<dim3(M1_ / 4), blk, 0, stream>>>(R_loc, pp_ln_g, pp_ln_b);

  // summaries -> h
  gemm_mfma<9, 0, 0, 0><<<dim3(4, 256), blk, 0, stream>>>(
      (const float*)R_loc, sumT, sum_b, R_h, BN_, 256, 256, 256, 256,
      nullptr, nullptr, nullptr);

  // ---- message-passing rounds ----
  unsigned short* hsnB = (unsigned short*)R_b1;
  unsigned short* UB   = (unsigned short*)R_b2;
  for (int step = 0; step < 4; ++step) {
    gemm_mfma<0, 0, 0, 1><<<dim3(8, 256), blk, 0, stream>>>(
        R_h, W1cT, R_bH, hsnB, BN_, 512, 256, 256, 512,
        nullptr, nullptr, nullptr);
    smsg_k<<<dim3(BN_ / 4), blk, 0, stream>>>(hsnB, R_b3);
    gemm_mfma<3, 0, 1, 1><<<dim3(4, 256), blk, 0, stream>>>(
        R_h, u1cT, R_bU, UB, BN_, 256, 512, 512, 256,
        R_b3, nullptr, nullptr);
    gemm_mfma<7, 0, 0, 0><<<dim3(4, 256), blk, 0, stream>>>(
        (const float*)UB, u2T, upd_b2, R_b1, BN_, 256, 256, 256, 256,
        nullptr, nullptr, nullptr);
    if (step == 3) {
      ln_k<3><<<dim3(BN_ / 4), blk, 0, stream>>>(
          R_h, R_b1, mp_ln_g, mp_ln_b, R_hp, R_outp);
    } else {
      ln_k<0><<<dim3(BN_ / 4), blk, 0, stream>>>(
          R_h, R_b1, mp_ln_g, mp_ln_b, nullptr, nullptr);
      if (step == 2) {
        halt1_k<<<dim3(32, 16), blk, 0, stream>>>(R_h, halt_w, R_part);
        halt2_k<<<dim3(1), dim3(64), 0, stream>>>(R_part, halt_b, R_hp);
        out2_k<<<dim3(BN_), blk, 0, stream>>>(R_h, R_hp, R_outp);
      }
    }
  }

  // ---- sparse retrieval attention ----
  unsigned short* qb   = (unsigned short*)R_b3;
  unsigned short* kb   = qb + SZ_Q;             // BN*256 shorts each
  unsigned short* vb   = (unsigned short*)R_rp;
  unsigned short* rpre = vb + SZ_Q;
  float* sc = R_b1;                             // 32*512*512 f32 = b1+b2
  gemm_mfma<0, 0, 0, 1><<<dim3(4, 256), blk, 0, stream>>>(
      R_outp, qT, q_b, qb, BN_, 256, 256, 256, 256, nullptr, nullptr, nullptr);
  gemm_mfma<0, 0, 0, 1><<<dim3(4, 256), blk, 0, stream>>>(
      R_outp, kTt, k_b, kb, BN_, 256, 256, 256, 256, nullptr, nullptr, nullptr);
  gemm_mfma<0, 0, 0, 1><<<dim3(4, 256), blk, 0, stream>>>(
      R_outp, vT, v_b, vb, BN_, 256, 256, 256, 256, nullptr, nullptr, nullptr);
  scores_tri<<<dim3(1152), blk, 0, stream>>>(qb, kb, sc);
  topk_k<<<dim3(BN_ / 4), blk, 0, stream>>>(sc, vb, rpre);

  float* retr  = R_b3;   // qb/kb dead
  float* broad = R_h;    // h dead
  gemm_mfma<7, 0, 0, 0><<<dim3(4, 256), blk, 0, stream>>>(
      (const float*)rpre, oT, o_b, retr, BN_, 256, 256, 256, 256,
      nullptr, nullptr, nullptr);
  gemm_mfma<5, 0, 0, 0><<<dim3(4, 256), blk, 0, stream>>>(
      R_outp, brT, br_b, broad, BN_, 256, 256, 256, 256,
      retr, nullptr, nullptr);

  // final LN + convert -> Abuf (b1+b2, sc dead), head GEMM -> logits
  unsigned short* Abuf = (unsigned short*)R_b1;
  ln_cvt_k<<<dim3(M1_ / 4), blk, 0, stream>>>(R_loc, broad, f_ln_g, f_ln_b, Abuf);
  gemm_mfma<7, 0, 0, 0><<<dim3(4, 1024), blk, 0, stream>>>(
      (const float*)Abuf, headT, nullptr, logits, M1_, 256, 256, 256, 256,
      nullptr, nullptr, nullptr);

  kl_k<<<dim3(1), dim3(64), 0, stream>>>(R_hp, logits + (size_t)M1_ * 256);
}